// Round 1
// baseline (418.193 us; speedup 1.0000x reference)
//
#include <hip/hip_runtime.h>

#define M_TOK 8192
#define N_OUT 4096
#define K_IN  4096

typedef __attribute__((ext_vector_type(8))) short bf16x8;
typedef __attribute__((ext_vector_type(4))) float f32x4;
typedef __attribute__((ext_vector_type(8))) unsigned short u16x8;

__device__ __forceinline__ unsigned short f2bf_rne(float f) {
    unsigned int u = __float_as_uint(f);
    u += 0x7fffu + ((u >> 16) & 1u);
    return (unsigned short)(u >> 16);
}

// exact for small integers (low 16 bits of the f32 pattern are zero)
__device__ __forceinline__ unsigned short i2bf_exact(int v) {
    return (unsigned short)(__float_as_uint((float)v) >> 16);
}

// ---------------- pre-convert kernels ----------------

__global__ void cvt_x_kernel(const float* __restrict__ x, unsigned short* __restrict__ o) {
    const int n8 = (M_TOK * K_IN) / 8;  // 4194304
    const int stride = gridDim.x * blockDim.x;
    for (int t = blockIdx.x * blockDim.x + threadIdx.x; t < n8; t += stride) {
        float4 a = reinterpret_cast<const float4*>(x)[2 * t];
        float4 b = reinterpret_cast<const float4*>(x)[2 * t + 1];
        u16x8 r;
        r[0] = f2bf_rne(a.x); r[1] = f2bf_rne(a.y);
        r[2] = f2bf_rne(a.z); r[3] = f2bf_rne(a.w);
        r[4] = f2bf_rne(b.x); r[5] = f2bf_rne(b.y);
        r[6] = f2bf_rne(b.z); r[7] = f2bf_rne(b.w);
        reinterpret_cast<u16x8*>(o)[t] = r;
    }
}

__global__ void cvt_w_kernel(const int* __restrict__ w, unsigned short* __restrict__ o) {
    const int n8 = (N_OUT * K_IN) / 8;  // 2097152
    const int stride = gridDim.x * blockDim.x;
    for (int t = blockIdx.x * blockDim.x + threadIdx.x; t < n8; t += stride) {
        int4 a = reinterpret_cast<const int4*>(w)[2 * t];
        int4 b = reinterpret_cast<const int4*>(w)[2 * t + 1];
        u16x8 r;
        r[0] = i2bf_exact(a.x); r[1] = i2bf_exact(a.y);
        r[2] = i2bf_exact(a.z); r[3] = i2bf_exact(a.w);
        r[4] = i2bf_exact(b.x); r[5] = i2bf_exact(b.y);
        r[6] = i2bf_exact(b.z); r[7] = i2bf_exact(b.w);
        reinterpret_cast<u16x8*>(o)[t] = r;
    }
}

// ---------------- GEMM ----------------
// C[M,N] = Xbf[M,K] * Wbf[N,K]^T  (both operands stored row-major [row][k])
// 128x128 tile, BK=32, 256 threads = 4 waves (2x2), each wave 64x64 out
// = 4x4 fragments of v_mfma_f32_16x16x32_bf16.
// Epilogue: out = acc * (row_scales[col]/127) + bias[col].

template <bool PRECONV>
__global__ __launch_bounds__(256) void qgemm_kernel(
    const float* __restrict__ x,
    const int* __restrict__ wq,
    const unsigned short* __restrict__ xbf,
    const unsigned short* __restrict__ wbf,
    const float* __restrict__ row_scales,
    const float* __restrict__ bias,
    float* __restrict__ out)
{
    constexpr int BM = 128, BN = 128, BK = 32;
    constexpr int LSTR = PRECONV ? BK : (BK + 8);  // pad only when reg-staged
    constexpr int NKT = K_IN / BK;                  // 128

    __shared__ unsigned short As[2][BM * LSTR];
    __shared__ unsigned short Bs[2][BN * LSTR];

    const int tid  = threadIdx.x;
    const int lane = tid & 63;
    const int wave = tid >> 6;
    const int wrow = wave >> 1;  // 0..1
    const int wcol = wave & 1;   // 0..1

    const int nbn = N_OUT / BN;  // 32
    const int bm = blockIdx.x / nbn;
    const int bn = blockIdx.x % nbn;

    f32x4 acc[4][4];
#pragma unroll
    for (int i = 0; i < 4; ++i)
#pragma unroll
        for (int j = 0; j < 4; ++j)
#pragma unroll
            for (int r = 0; r < 4; ++r) acc[i][j][r] = 0.0f;

    // fused-path staging registers
    float4 a_ld[4];
    int4 b_ld[4];

    // ---- staging helpers (inlined via lambdas) ----
    auto stage_glds = [&](int buf, int kt) {
        // A tile: 128 rows x 32 bf16 = 8 KiB = 8 chunks of 1 KiB; same for B.
        // wave w issues A chunks {2w,2w+1} and B chunks {2w,2w+1}.
#pragma unroll
        for (int c2 = 0; c2 < 2; ++c2) {
            const int c = wave * 2 + c2;
            {
                const int row = bm * BM + c * 16 + (lane >> 2);
                const unsigned short* g =
                    xbf + (size_t)row * K_IN + kt * BK + (lane & 3) * 8;
                __builtin_amdgcn_global_load_lds(
                    (const __attribute__((address_space(1))) void*)g,
                    (__attribute__((address_space(3))) void*)&As[buf][c * 512],
                    16, 0, 0);
            }
            {
                const int row = bn * BN + c * 16 + (lane >> 2);
                const unsigned short* g =
                    wbf + (size_t)row * K_IN + kt * BK + (lane & 3) * 8;
                __builtin_amdgcn_global_load_lds(
                    (const __attribute__((address_space(1))) void*)g,
                    (__attribute__((address_space(3))) void*)&Bs[buf][c * 512],
                    16, 0, 0);
            }
        }
    };

    auto stage_load = [&](int kt) {
        // A: 4 passes of float4; thread t -> row (t>>3)+32p, kchunk (t&7)*4
#pragma unroll
        for (int p = 0; p < 4; ++p) {
            const int row = bm * BM + (tid >> 3) + p * 32;
            a_ld[p] = *reinterpret_cast<const float4*>(
                x + (size_t)row * K_IN + kt * BK + (tid & 7) * 4);
        }
        // B (int32 weights): thread t -> row t>>1, 16 consecutive k
        {
            const int row = bn * BN + (tid >> 1);
            const int* base = wq + (size_t)row * K_IN + kt * BK + (tid & 1) * 16;
#pragma unroll
            for (int q = 0; q < 4; ++q)
                b_ld[q] = reinterpret_cast<const int4*>(base)[q];
        }
    };

    auto stage_write = [&](int buf) {
#pragma unroll
        for (int p = 0; p < 4; ++p) {
            const int row = (tid >> 3) + p * 32;
            ushort4 v;
            v.x = f2bf_rne(a_ld[p].x); v.y = f2bf_rne(a_ld[p].y);
            v.z = f2bf_rne(a_ld[p].z); v.w = f2bf_rne(a_ld[p].w);
            *reinterpret_cast<ushort4*>(&As[buf][row * LSTR + (tid & 7) * 4]) = v;
        }
        {
            const int row = tid >> 1;
            u16x8 r0, r1;
            r0[0] = i2bf_exact(b_ld[0].x); r0[1] = i2bf_exact(b_ld[0].y);
            r0[2] = i2bf_exact(b_ld[0].z); r0[3] = i2bf_exact(b_ld[0].w);
            r0[4] = i2bf_exact(b_ld[1].x); r0[5] = i2bf_exact(b_ld[1].y);
            r0[6] = i2bf_exact(b_ld[1].z); r0[7] = i2bf_exact(b_ld[1].w);
            r1[0] = i2bf_exact(b_ld[2].x); r1[1] = i2bf_exact(b_ld[2].y);
            r1[2] = i2bf_exact(b_ld[2].z); r1[3] = i2bf_exact(b_ld[2].w);
            r1[4] = i2bf_exact(b_ld[3].x); r1[5] = i2bf_exact(b_ld[3].y);
            r1[6] = i2bf_exact(b_ld[3].z); r1[7] = i2bf_exact(b_ld[3].w);
            unsigned short* dst = &Bs[buf][row * LSTR + (tid & 1) * 16];
            *reinterpret_cast<u16x8*>(dst) = r0;
            *reinterpret_cast<u16x8*>(dst + 8) = r1;
        }
    };

    // ---- prologue ----
    if constexpr (PRECONV) {
        stage_glds(0, 0);
    } else {
        stage_load(0);
        stage_write(0);
    }
    __syncthreads();  // drains vmcnt/lgkmcnt

    // ---- main loop: one barrier per K-step, double-buffered LDS ----
    int buf = 0;
    for (int kt = 0; kt < NKT; ++kt) {
        // issue next tile's loads early (hide HBM latency under MFMA)
        if constexpr (PRECONV) {
            if (kt + 1 < NKT) stage_glds(buf ^ 1, kt + 1);
        } else {
            if (kt + 1 < NKT) stage_load(kt + 1);
        }

        // LDS -> fragments
        const int koff = (lane >> 4) * 8;
        const int rA = lane & 15;
        bf16x8 af[4], bfr[4];
#pragma unroll
        for (int fm = 0; fm < 4; ++fm)
            af[fm] = *reinterpret_cast<const bf16x8*>(
                &As[buf][(wrow * 64 + fm * 16 + rA) * LSTR + koff]);
#pragma unroll
        for (int fn = 0; fn < 4; ++fn)
            bfr[fn] = *reinterpret_cast<const bf16x8*>(
                &Bs[buf][(wcol * 64 + fn * 16 + rA) * LSTR + koff]);

#pragma unroll
        for (int fm = 0; fm < 4; ++fm)
#pragma unroll
            for (int fn = 0; fn < 4; ++fn)
                acc[fm][fn] = __builtin_amdgcn_mfma_f32_16x16x32_bf16(
                    af[fm], bfr[fn], acc[fm][fn], 0, 0, 0);

        if constexpr (!PRECONV) {
            if (kt + 1 < NKT) stage_write(buf ^ 1);
        }
        __syncthreads();
        buf ^= 1;
    }

    // ---- epilogue: dequant scale + bias, fp32 store ----
    const int row0 = bm * BM + wrow * 64;
    const int col0 = bn * BN + wcol * 64;
    const int cl = lane & 15;
    const int rgrp = lane >> 4;
#pragma unroll
    for (int fn = 0; fn < 4; ++fn) {
        const int col = col0 + fn * 16 + cl;
        const float sc = row_scales[col] * (1.0f / 127.0f);
        const float bs = bias[col];
#pragma unroll
        for (int fm = 0; fm < 4; ++fm) {
#pragma unroll
            for (int r = 0; r < 4; ++r) {
                const int row = row0 + fm * 16 + rgrp * 4 + r;
                out[(size_t)row * N_OUT + col] = acc[fm][fn][r] * sc + bs;
            }
        }
    }
}

// ---------------- launch ----------------

extern "C" void kernel_launch(void* const* d_in, const int* in_sizes, int n_in,
                              void* d_out, int out_size, void* d_ws, size_t ws_size,
                              hipStream_t stream) {
    const float* x = (const float*)d_in[0];
    const int* wq = (const int*)d_in[1];          // int8 in reference -> int32 buffer
    const float* row_scales = (const float*)d_in[2];
    const float* bias = (const float*)d_in[3];
    float* out = (float*)d_out;

    const size_t xbf_bytes = (size_t)M_TOK * K_IN * 2;  // 64 MiB
    const size_t wbf_bytes = (size_t)N_OUT * K_IN * 2;  // 32 MiB
    const int nblocks = (M_TOK / 128) * (N_OUT / 128);  // 2048

    if (ws_size >= xbf_bytes + wbf_bytes) {
        unsigned short* xbf = (unsigned short*)d_ws;
        unsigned short* wbf = (unsigned short*)((char*)d_ws + xbf_bytes);
        cvt_x_kernel<<<2048, 256, 0, stream>>>(x, xbf);
        cvt_w_kernel<<<1024, 256, 0, stream>>>(wq, wbf);
        qgemm_kernel<true><<<nblocks, 256, 0, stream>>>(
            x, wq, xbf, wbf, row_scales, bias, out);
    } else {
        qgemm_kernel<false><<<nblocks, 256, 0, stream>>>(
            x, wq, nullptr, nullptr, row_scales, bias, out);
    }
}

// Round 2
// 305.166 us; speedup vs baseline: 1.3704x; 1.3704x over previous
//
#include <hip/hip_runtime.h>

#define M_TOK 8192
#define N_OUT 4096
#define K_IN  4096

typedef __attribute__((ext_vector_type(8))) short bf16x8;
typedef __attribute__((ext_vector_type(4))) float f32x4;
typedef __attribute__((ext_vector_type(8))) unsigned short u16x8;

__device__ __forceinline__ unsigned short f2bf_rne(float f) {
    unsigned int u = __float_as_uint(f);
    u += 0x7fffu + ((u >> 16) & 1u);
    return (unsigned short)(u >> 16);
}

// exact for small integers (low 16 bits of the f32 pattern are zero)
__device__ __forceinline__ unsigned short i2bf_exact(int v) {
    return (unsigned short)(__float_as_uint((float)v) >> 16);
}

// ---------------- pre-convert kernels ----------------

__global__ void cvt_x_kernel(const float* __restrict__ x, unsigned short* __restrict__ o) {
    const int n8 = (M_TOK * K_IN) / 8;
    const int stride = gridDim.x * blockDim.x;
    for (int t = blockIdx.x * blockDim.x + threadIdx.x; t < n8; t += stride) {
        float4 a = reinterpret_cast<const float4*>(x)[2 * t];
        float4 b = reinterpret_cast<const float4*>(x)[2 * t + 1];
        u16x8 r;
        r[0] = f2bf_rne(a.x); r[1] = f2bf_rne(a.y);
        r[2] = f2bf_rne(a.z); r[3] = f2bf_rne(a.w);
        r[4] = f2bf_rne(b.x); r[5] = f2bf_rne(b.y);
        r[6] = f2bf_rne(b.z); r[7] = f2bf_rne(b.w);
        reinterpret_cast<u16x8*>(o)[t] = r;
    }
}

__global__ void cvt_w_kernel(const int* __restrict__ w, unsigned short* __restrict__ o) {
    const int n8 = (N_OUT * K_IN) / 8;
    const int stride = gridDim.x * blockDim.x;
    for (int t = blockIdx.x * blockDim.x + threadIdx.x; t < n8; t += stride) {
        int4 a = reinterpret_cast<const int4*>(w)[2 * t];
        int4 b = reinterpret_cast<const int4*>(w)[2 * t + 1];
        u16x8 r;
        r[0] = i2bf_exact(a.x); r[1] = i2bf_exact(a.y);
        r[2] = i2bf_exact(a.z); r[3] = i2bf_exact(a.w);
        r[4] = i2bf_exact(b.x); r[5] = i2bf_exact(b.y);
        r[6] = i2bf_exact(b.z); r[7] = i2bf_exact(b.w);
        reinterpret_cast<u16x8*>(o)[t] = r;
    }
}

// ---------------- 256x256 phase-pipelined GEMM ----------------
// C[M,N] = Xbf[M,K] * Wbf[N,K]^T, 256x256 tile, BK=32 K-tiles in a ring of 4
// LDS slots (128 KiB total). 512 threads = 8 waves (2x4); each wave owns
// 128x64 = acc[8][4] fragments of v_mfma_f32_16x16x32_bf16.
// Per K-tile: 2 phases; each phase = {ds_read frags; stage (2x glds);
// barrier; lgkmcnt(0); setprio(1); 16 MFMA; setprio(0); barrier}.
// Boundary s_waitcnt vmcnt(8) (counted, never 0 in steady state);
// 3 K-tiles prefetched ahead.
// LDS rows are 64B (32 bf16); XOR swizzle granule' = granule ^ ((row>>1)&3),
// applied as inverse-pre-swizzled GLOBAL source (linear glds dest) + swizzled
// ds_read address (rule 21c).

#define BK 32
#define NKT (K_IN / BK)          // 128
#define SLOT_BYTES 16384         // 256 rows x 64 B
#define NSLOT 4

__global__ __launch_bounds__(512, 2) void qgemm8_kernel(
    const unsigned short* __restrict__ xbf,
    const unsigned short* __restrict__ wbf,
    const float* __restrict__ row_scales,
    const float* __restrict__ bias,
    float* __restrict__ out)
{
    __shared__ __align__(16) char smem[2 * NSLOT * SLOT_BYTES];  // A slots [0,64K), B slots [64K,128K)

    const int tid = threadIdx.x;
    const int l = tid & 63;
    const int w = tid >> 6;
    const int wr = w >> 2;   // 0..1
    const int wc = w & 3;    // 0..3

    // XCD-aware bijective swizzle (nwg = 512, 512 % 8 == 0)
    const int bid = blockIdx.x;
    const int swz = (bid & 7) * 64 + (bid >> 3);
    const int bm = swz >> 4;   // 0..31
    const int bn = swz & 15;   // 0..15

    // ---- staging addressing (linear LDS dest; pre-swizzled global src) ----
    const int rloc0 = tid >> 2;                       // row 0..127 (j adds 128)
    const int gs = (l & 3) ^ ((l >> 3) & 3);          // source granule for this lane
    const unsigned short* aSrc = xbf + (size_t)(bm * 256 + rloc0) * K_IN + gs * 8;
    const unsigned short* bSrc = wbf + (size_t)(bn * 256 + rloc0) * K_IN + gs * 8;
    char* aDst0 = smem + w * 1024;                    // wave-uniform; HW adds lane*16
    char* bDst0 = smem + NSLOT * SLOT_BYTES + w * 1024;

    // ---- fragment ds_read offsets (swizzled) ----
    const int rA = l & 15;
    const int g = l >> 4;                              // k-granule 0..3
    const int gsw = ((g ^ ((rA >> 1) & 3)) << 4);      // swizzled granule byte offset
    int aoff[8], boff[4];
#pragma unroll
    for (int fm = 0; fm < 8; ++fm)
        aoff[fm] = (wr * 128 + fm * 16 + rA) * 64 + gsw;
#pragma unroll
    for (int fn = 0; fn < 4; ++fn)
        boff[fn] = (wc * 64 + fn * 16 + rA) * 64 + gsw;

    f32x4 acc[8][4];
#pragma unroll
    for (int i = 0; i < 8; ++i)
#pragma unroll
        for (int j = 0; j < 4; ++j)
#pragma unroll
            for (int r = 0; r < 4; ++r) acc[i][j][r] = 0.0f;

    auto stageA = [&](int tt) {
        const int sb = (tt & 3) * SLOT_BYTES;
#pragma unroll
        for (int j = 0; j < 2; ++j)
            __builtin_amdgcn_global_load_lds(
                (const __attribute__((address_space(1))) void*)(aSrc + (size_t)j * 128 * K_IN + tt * BK),
                (__attribute__((address_space(3))) void*)(aDst0 + sb + j * 8192),
                16, 0, 0);
    };
    auto stageB = [&](int tt) {
        const int sb = (tt & 3) * SLOT_BYTES;
#pragma unroll
        for (int j = 0; j < 2; ++j)
            __builtin_amdgcn_global_load_lds(
                (const __attribute__((address_space(1))) void*)(bSrc + (size_t)j * 128 * K_IN + tt * BK),
                (__attribute__((address_space(3))) void*)(bDst0 + sb + j * 8192),
                16, 0, 0);
    };

    // ---- prologue: stage tiles 0,1,2 (12 loads); tile 0 ready after vmcnt(8) ----
    stageA(0); stageB(0);
    stageA(1); stageB(1);
    stageA(2); stageB(2);
    asm volatile("s_waitcnt vmcnt(8)" ::: "memory");
    __builtin_amdgcn_sched_barrier(0);
    __builtin_amdgcn_s_barrier();

    // ---- main loop ----
    for (int t = 0; t < NKT; ++t) {
        const char* Ab = smem + (t & 3) * SLOT_BYTES;
        const char* Bb = smem + NSLOT * SLOT_BYTES + (t & 3) * SLOT_BYTES;
        const bool st = (t + 3 < NKT);

        // ===== phase 0: B frags + A frags 0-3; stage A(t+3); MFMA fm 0-3 =====
        bf16x8 b0 = *reinterpret_cast<const bf16x8*>(Bb + boff[0]);
        bf16x8 b1 = *reinterpret_cast<const bf16x8*>(Bb + boff[1]);
        bf16x8 b2 = *reinterpret_cast<const bf16x8*>(Bb + boff[2]);
        bf16x8 b3 = *reinterpret_cast<const bf16x8*>(Bb + boff[3]);
        bf16x8 a0 = *reinterpret_cast<const bf16x8*>(Ab + aoff[0]);
        bf16x8 a1 = *reinterpret_cast<const bf16x8*>(Ab + aoff[1]);
        bf16x8 a2 = *reinterpret_cast<const bf16x8*>(Ab + aoff[2]);
        bf16x8 a3 = *reinterpret_cast<const bf16x8*>(Ab + aoff[3]);
        if (st) stageA(t + 3);
        asm volatile("" ::: "memory");
        __builtin_amdgcn_sched_barrier(0);
        __builtin_amdgcn_s_barrier();
        asm volatile("s_waitcnt lgkmcnt(0)" ::: "memory");
        __builtin_amdgcn_sched_barrier(0);
        __builtin_amdgcn_s_setprio(1);
        acc[0][0] = __builtin_amdgcn_mfma_f32_16x16x32_bf16(a0, b0, acc[0][0], 0, 0, 0);
        acc[0][1] = __builtin_amdgcn_mfma_f32_16x16x32_bf16(a0, b1, acc[0][1], 0, 0, 0);
        acc[0][2] = __builtin_amdgcn_mfma_f32_16x16x32_bf16(a0, b2, acc[0][2], 0, 0, 0);
        acc[0][3] = __builtin_amdgcn_mfma_f32_16x16x32_bf16(a0, b3, acc[0][3], 0, 0, 0);
        acc[1][0] = __builtin_amdgcn_mfma_f32_16x16x32_bf16(a1, b0, acc[1][0], 0, 0, 0);
        acc[1][1] = __builtin_amdgcn_mfma_f32_16x16x32_bf16(a1, b1, acc[1][1], 0, 0, 0);
        acc[1][2] = __builtin_amdgcn_mfma_f32_16x16x32_bf16(a1, b2, acc[1][2], 0, 0, 0);
        acc[1][3] = __builtin_amdgcn_mfma_f32_16x16x32_bf16(a1, b3, acc[1][3], 0, 0, 0);
        acc[2][0] = __builtin_amdgcn_mfma_f32_16x16x32_bf16(a2, b0, acc[2][0], 0, 0, 0);
        acc[2][1] = __builtin_amdgcn_mfma_f32_16x16x32_bf16(a2, b1, acc[2][1], 0, 0, 0);
        acc[2][2] = __builtin_amdgcn_mfma_f32_16x16x32_bf16(a2, b2, acc[2][2], 0, 0, 0);
        acc[2][3] = __builtin_amdgcn_mfma_f32_16x16x32_bf16(a2, b3, acc[2][3], 0, 0, 0);
        acc[3][0] = __builtin_amdgcn_mfma_f32_16x16x32_bf16(a3, b0, acc[3][0], 0, 0, 0);
        acc[3][1] = __builtin_amdgcn_mfma_f32_16x16x32_bf16(a3, b1, acc[3][1], 0, 0, 0);
        acc[3][2] = __builtin_amdgcn_mfma_f32_16x16x32_bf16(a3, b2, acc[3][2], 0, 0, 0);
        acc[3][3] = __builtin_amdgcn_mfma_f32_16x16x32_bf16(a3, b3, acc[3][3], 0, 0, 0);
        __builtin_amdgcn_s_setprio(0);
        __builtin_amdgcn_s_barrier();

        // ===== phase 1: A frags 4-7 (B reused); stage B(t+3); MFMA fm 4-7 =====
        bf16x8 a4 = *reinterpret_cast<const bf16x8*>(Ab + aoff[4]);
        bf16x8 a5 = *reinterpret_cast<const bf16x8*>(Ab + aoff[5]);
        bf16x8 a6 = *reinterpret_cast<const bf16x8*>(Ab + aoff[6]);
        bf16x8 a7 = *reinterpret_cast<const bf16x8*>(Ab + aoff[7]);
        if (st) stageB(t + 3);
        asm volatile("" ::: "memory");
        __builtin_amdgcn_sched_barrier(0);
        __builtin_amdgcn_s_barrier();
        asm volatile("s_waitcnt lgkmcnt(0)" ::: "memory");
        __builtin_amdgcn_sched_barrier(0);
        __builtin_amdgcn_s_setprio(1);
        acc[4][0] = __builtin_amdgcn_mfma_f32_16x16x32_bf16(a4, b0, acc[4][0], 0, 0, 0);
        acc[4][1] = __builtin_amdgcn_mfma_f32_16x16x32_bf16(a4, b1, acc[4][1], 0, 0, 0);
        acc[4][2] = __builtin_amdgcn_mfma_f32_16x16x32_bf16(a4, b2, acc[4][2], 0, 0, 0);
        acc[4][3] = __builtin_amdgcn_mfma_f32_16x16x32_bf16(a4, b3, acc[4][3], 0, 0, 0);
        acc[5][0] = __builtin_amdgcn_mfma_f32_16x16x32_bf16(a5, b0, acc[5][0], 0, 0, 0);
        acc[5][1] = __builtin_amdgcn_mfma_f32_16x16x32_bf16(a5, b1, acc[5][1], 0, 0, 0);
        acc[5][2] = __builtin_amdgcn_mfma_f32_16x16x32_bf16(a5, b2, acc[5][2], 0, 0, 0);
        acc[5][3] = __builtin_amdgcn_mfma_f32_16x16x32_bf16(a5, b3, acc[5][3], 0, 0, 0);
        acc[6][0] = __builtin_amdgcn_mfma_f32_16x16x32_bf16(a6, b0, acc[6][0], 0, 0, 0);
        acc[6][1] = __builtin_amdgcn_mfma_f32_16x16x32_bf16(a6, b1, acc[6][1], 0, 0, 0);
        acc[6][2] = __builtin_amdgcn_mfma_f32_16x16x32_bf16(a6, b2, acc[6][2], 0, 0, 0);
        acc[6][3] = __builtin_amdgcn_mfma_f32_16x16x32_bf16(a6, b3, acc[6][3], 0, 0, 0);
        acc[7][0] = __builtin_amdgcn_mfma_f32_16x16x32_bf16(a7, b0, acc[7][0], 0, 0, 0);
        acc[7][1] = __builtin_amdgcn_mfma_f32_16x16x32_bf16(a7, b1, acc[7][1], 0, 0, 0);
        acc[7][2] = __builtin_amdgcn_mfma_f32_16x16x32_bf16(a7, b2, acc[7][2], 0, 0, 0);
        acc[7][3] = __builtin_amdgcn_mfma_f32_16x16x32_bf16(a7, b3, acc[7][3], 0, 0, 0);
        __builtin_amdgcn_s_setprio(0);

        // boundary: counted vmcnt (tile t+1 complete), never 0 in steady state
        if (t + 3 < NKT) {
            asm volatile("s_waitcnt vmcnt(8)" ::: "memory");
        } else if (t + 2 < NKT) {
            asm volatile("s_waitcnt vmcnt(4)" ::: "memory");
        } else if (t + 1 < NKT) {
            asm volatile("s_waitcnt vmcnt(0)" ::: "memory");
        }
        if (t + 1 < NKT) {
            __builtin_amdgcn_sched_barrier(0);
            __builtin_amdgcn_s_barrier();
        }
    }

    // ---- epilogue: dequant scale + bias, fp32 store ----
    const int cl = l & 15;
    const int rg = l >> 4;
    const size_t rowbase = (size_t)(bm * 256 + wr * 128);
#pragma unroll
    for (int fn = 0; fn < 4; ++fn) {
        const int col = bn * 256 + wc * 64 + fn * 16 + cl;
        const float sc = row_scales[col] * (1.0f / 127.0f);
        const float bs = bias[col];
#pragma unroll
        for (int fm = 0; fm < 8; ++fm) {
#pragma unroll
            for (int r = 0; r < 4; ++r) {
                const size_t row = rowbase + fm * 16 + rg * 4 + r;
                out[row * N_OUT + col] = acc[fm][fn][r] * sc + bs;
            }
        }
    }
}

// ---------------- launch ----------------

extern "C" void kernel_launch(void* const* d_in, const int* in_sizes, int n_in,
                              void* d_out, int out_size, void* d_ws, size_t ws_size,
                              hipStream_t stream) {
    const float* x = (const float*)d_in[0];
    const int* wq = (const int*)d_in[1];
    const float* row_scales = (const float*)d_in[2];
    const float* bias = (const float*)d_in[3];
    float* out = (float*)d_out;

    const size_t xbf_bytes = (size_t)M_TOK * K_IN * 2;  // 64 MiB
    const size_t wbf_bytes = (size_t)N_OUT * K_IN * 2;  // 32 MiB

    unsigned short* xbf = (unsigned short*)d_ws;
    unsigned short* wbf = (unsigned short*)((char*)d_ws + xbf_bytes);
    (void)ws_size; (void)xbf_bytes; (void)wbf_bytes;

    cvt_x_kernel<<<2048, 256, 0, stream>>>(x, xbf);
    cvt_w_kernel<<<1024, 256, 0, stream>>>(wq, wbf);

    const int nblocks = (M_TOK / 256) * (N_OUT / 256);  // 512
    qgemm8_kernel<<<nblocks, 512, 0, stream>>>(xbf, wbf, row_scales, bias, out);
}

// Round 3
// 297.448 us; speedup vs baseline: 1.4059x; 1.0259x over previous
//
#include <hip/hip_runtime.h>

#define M_TOK 8192
#define N_OUT 4096
#define K_IN  4096

#define AS1 __attribute__((address_space(1)))
#define AS3 __attribute__((address_space(3)))

typedef __attribute__((ext_vector_type(8))) short bf16x8;
typedef __attribute__((ext_vector_type(4))) float f32x4;
typedef __attribute__((ext_vector_type(8))) unsigned short u16x8;

__device__ __forceinline__ unsigned short f2bf_rne(float f) {
    unsigned int u = __float_as_uint(f);
    u += 0x7fffu + ((u >> 16) & 1u);
    return (unsigned short)(u >> 16);
}

// exact for small integers (low 16 bits of the f32 pattern are zero)
__device__ __forceinline__ unsigned short i2bf_exact(int v) {
    return (unsigned short)(__float_as_uint((float)v) >> 16);
}

// inline-asm ds_read_b128: invisible to compiler AA (no "memory" clobber);
// ordering/synchronization is OURS via counted lgkmcnt + sched_barrier(0).
template <int OFF>
__device__ __forceinline__ bf16x8 dsr(unsigned addr) {
    bf16x8 r;
    asm volatile("ds_read_b128 %0, %1 offset:%2" : "=v"(r) : "v"(addr), "n"(OFF));
    return r;
}

// ---------------- pre-convert kernels ----------------

__global__ void cvt_x_kernel(const float* __restrict__ x, unsigned short* __restrict__ o) {
    const int n8 = (M_TOK * K_IN) / 8;
    const int stride = gridDim.x * blockDim.x;
    for (int t = blockIdx.x * blockDim.x + threadIdx.x; t < n8; t += stride) {
        float4 a = reinterpret_cast<const float4*>(x)[2 * t];
        float4 b = reinterpret_cast<const float4*>(x)[2 * t + 1];
        u16x8 r;
        r[0] = f2bf_rne(a.x); r[1] = f2bf_rne(a.y);
        r[2] = f2bf_rne(a.z); r[3] = f2bf_rne(a.w);
        r[4] = f2bf_rne(b.x); r[5] = f2bf_rne(b.y);
        r[6] = f2bf_rne(b.z); r[7] = f2bf_rne(b.w);
        reinterpret_cast<u16x8*>(o)[t] = r;
    }
}

__global__ void cvt_w_kernel(const int* __restrict__ w, unsigned short* __restrict__ o) {
    const int n8 = (N_OUT * K_IN) / 8;
    const int stride = gridDim.x * blockDim.x;
    for (int t = blockIdx.x * blockDim.x + threadIdx.x; t < n8; t += stride) {
        int4 a = reinterpret_cast<const int4*>(w)[2 * t];
        int4 b = reinterpret_cast<const int4*>(w)[2 * t + 1];
        u16x8 r;
        r[0] = i2bf_exact(a.x); r[1] = i2bf_exact(a.y);
        r[2] = i2bf_exact(a.z); r[3] = i2bf_exact(a.w);
        r[4] = i2bf_exact(b.x); r[5] = i2bf_exact(b.y);
        r[6] = i2bf_exact(b.z); r[7] = i2bf_exact(b.w);
        reinterpret_cast<u16x8*>(o)[t] = r;
    }
}

// ---------------- 256x256 pipelined GEMM, 1 barrier / K-tile ----------------
// C[M,N] = Xbf[M,K] * Wbf[N,K]^T, BK=32 K-tiles in a ring of 4 LDS slots
// (128 KiB). 512 threads = 8 waves (2x4); wave owns 128x64 = acc[8][4] of
// v_mfma_f32_16x16x32_bf16.
// Per K-tile: stageA(t+3); 12 asm ds_reads (a0-3, b0-3, a4-7); stageB(t+3);
// lgkmcnt(4) -> 16 MFMA (fm0-3); lgkmcnt(0) -> 16 MFMA (fm4-7);
// counted vmcnt(8) (never 0 in steady state); ONE s_barrier.
// Ring-4 + per-wave lgkm(0)-before-boundary makes single-barrier race-free.
// LDS swizzle: granule' = granule ^ ((row>>1)&3), inverse-pre-swizzled global
// source (linear glds dest) + swizzled ds_read addr (rule 21c).

#define BK 32
#define NKT (K_IN / BK)          // 128
#define SLOT_BYTES 16384         // 256 rows x 64 B
#define NSLOT 4

__global__ __launch_bounds__(512, 2) void qgemm8_kernel(
    const unsigned short* __restrict__ xbf,
    const unsigned short* __restrict__ wbf,
    const float* __restrict__ row_scales,
    const float* __restrict__ bias,
    float* __restrict__ out)
{
    __shared__ __align__(16) char smem[2 * NSLOT * SLOT_BYTES];  // A [0,64K), B [64K,128K)

    const int tid = threadIdx.x;
    const int l = tid & 63;
    const int w = tid >> 6;
    const int wr = w >> 2;   // 0..1
    const int wc = w & 3;    // 0..3

    // XCD-aware bijective swizzle (nwg = 512, 512 % 8 == 0)
    const int bid = blockIdx.x;
    const int swz = (bid & 7) * 64 + (bid >> 3);
    const int bm = swz >> 4;   // 0..31
    const int bn = swz & 15;   // 0..15

    // ---- staging addressing (linear LDS dest; pre-swizzled global src) ----
    const int rloc0 = tid >> 2;                       // row 0..127 (j adds 128)
    const int gs = (l & 3) ^ ((l >> 3) & 3);          // source granule for this lane
    const unsigned short* aSrc = xbf + (size_t)(bm * 256 + rloc0) * K_IN + gs * 8;
    const unsigned short* bSrc = wbf + (size_t)(bn * 256 + rloc0) * K_IN + gs * 8;
    char* aDst0 = smem + w * 1024;                    // wave-uniform; HW adds lane*16
    char* bDst0 = smem + NSLOT * SLOT_BYTES + w * 1024;

    // ---- fragment ds_read base addresses (swizzled) ----
    const unsigned sbase = (unsigned)(uintptr_t)(AS3 char*)smem;
    const int rA = l & 15;
    const int g = l >> 4;                              // k-granule 0..3
    const int gsw = ((g ^ ((rA >> 1) & 3)) << 4);      // swizzled granule byte offset
    const unsigned aoff_base = (unsigned)((wr * 128 + rA) * 64 + gsw);  // + fm*1024
    const unsigned boff_base = (unsigned)((wc * 64 + rA) * 64 + gsw);   // + fn*1024

    f32x4 acc[8][4];
#pragma unroll
    for (int i = 0; i < 8; ++i)
#pragma unroll
        for (int j = 0; j < 4; ++j)
#pragma unroll
            for (int r = 0; r < 4; ++r) acc[i][j][r] = 0.0f;

    auto stageA = [&](int tt) {
        const int sb = (tt & 3) * SLOT_BYTES;
#pragma unroll
        for (int j = 0; j < 2; ++j)
            __builtin_amdgcn_global_load_lds(
                (const AS1 void*)(aSrc + (size_t)j * 128 * K_IN + tt * BK),
                (AS3 void*)(aDst0 + sb + j * 8192), 16, 0, 0);
    };
    auto stageB = [&](int tt) {
        const int sb = (tt & 3) * SLOT_BYTES;
#pragma unroll
        for (int j = 0; j < 2; ++j)
            __builtin_amdgcn_global_load_lds(
                (const AS1 void*)(bSrc + (size_t)j * 128 * K_IN + tt * BK),
                (AS3 void*)(bDst0 + sb + j * 8192), 16, 0, 0);
    };

    // ---- prologue: stage tiles 0,1,2 (12 glds); tile 0 ready after vmcnt(8) ----
    stageA(0); stageB(0);
    stageA(1); stageB(1);
    stageA(2); stageB(2);
    asm volatile("s_waitcnt vmcnt(8)" ::: "memory");
    __builtin_amdgcn_sched_barrier(0);
    __builtin_amdgcn_s_barrier();
    __builtin_amdgcn_sched_barrier(0);

    // ---- main loop ----
    for (int t = 0; t < NKT; ++t) {
        const unsigned Asl = sbase + (unsigned)((t & 3) * SLOT_BYTES);
        const unsigned Bsl = Asl + (unsigned)(NSLOT * SLOT_BYTES);
        const unsigned aAddr = Asl + aoff_base;
        const unsigned bAddr = Bsl + boff_base;
        const bool st = (t + 3 < NKT);

        if (st) stageA(t + 3);

        // 12 ds_reads, fixed order: a0-3, b0-3, a4-7 (lgkm counts DS in order)
        bf16x8 a0 = dsr<0 * 1024>(aAddr);
        bf16x8 a1 = dsr<1 * 1024>(aAddr);
        bf16x8 a2 = dsr<2 * 1024>(aAddr);
        bf16x8 a3 = dsr<3 * 1024>(aAddr);
        bf16x8 b0 = dsr<0 * 1024>(bAddr);
        bf16x8 b1 = dsr<1 * 1024>(bAddr);
        bf16x8 b2 = dsr<2 * 1024>(bAddr);
        bf16x8 b3 = dsr<3 * 1024>(bAddr);
        bf16x8 a4 = dsr<4 * 1024>(aAddr);
        bf16x8 a5 = dsr<5 * 1024>(aAddr);
        bf16x8 a6 = dsr<6 * 1024>(aAddr);
        bf16x8 a7 = dsr<7 * 1024>(aAddr);

        if (st) stageB(t + 3);

        // cluster 1: needs first 8 reads (a0-3, b0-3); a4-7 drain underneath
        asm volatile("s_waitcnt lgkmcnt(4)" ::: "memory");
        __builtin_amdgcn_sched_barrier(0);
        __builtin_amdgcn_s_setprio(1);
        acc[0][0] = __builtin_amdgcn_mfma_f32_16x16x32_bf16(a0, b0, acc[0][0], 0, 0, 0);
        acc[0][1] = __builtin_amdgcn_mfma_f32_16x16x32_bf16(a0, b1, acc[0][1], 0, 0, 0);
        acc[0][2] = __builtin_amdgcn_mfma_f32_16x16x32_bf16(a0, b2, acc[0][2], 0, 0, 0);
        acc[0][3] = __builtin_amdgcn_mfma_f32_16x16x32_bf16(a0, b3, acc[0][3], 0, 0, 0);
        acc[1][0] = __builtin_amdgcn_mfma_f32_16x16x32_bf16(a1, b0, acc[1][0], 0, 0, 0);
        acc[1][1] = __builtin_amdgcn_mfma_f32_16x16x32_bf16(a1, b1, acc[1][1], 0, 0, 0);
        acc[1][2] = __builtin_amdgcn_mfma_f32_16x16x32_bf16(a1, b2, acc[1][2], 0, 0, 0);
        acc[1][3] = __builtin_amdgcn_mfma_f32_16x16x32_bf16(a1, b3, acc[1][3], 0, 0, 0);
        acc[2][0] = __builtin_amdgcn_mfma_f32_16x16x32_bf16(a2, b0, acc[2][0], 0, 0, 0);
        acc[2][1] = __builtin_amdgcn_mfma_f32_16x16x32_bf16(a2, b1, acc[2][1], 0, 0, 0);
        acc[2][2] = __builtin_amdgcn_mfma_f32_16x16x32_bf16(a2, b2, acc[2][2], 0, 0, 0);
        acc[2][3] = __builtin_amdgcn_mfma_f32_16x16x32_bf16(a2, b3, acc[2][3], 0, 0, 0);
        acc[3][0] = __builtin_amdgcn_mfma_f32_16x16x32_bf16(a3, b0, acc[3][0], 0, 0, 0);
        acc[3][1] = __builtin_amdgcn_mfma_f32_16x16x32_bf16(a3, b1, acc[3][1], 0, 0, 0);
        acc[3][2] = __builtin_amdgcn_mfma_f32_16x16x32_bf16(a3, b2, acc[3][2], 0, 0, 0);
        acc[3][3] = __builtin_amdgcn_mfma_f32_16x16x32_bf16(a3, b3, acc[3][3], 0, 0, 0);
        __builtin_amdgcn_s_setprio(0);

        // cluster 2: needs a4-7
        asm volatile("s_waitcnt lgkmcnt(0)" ::: "memory");
        __builtin_amdgcn_sched_barrier(0);
        __builtin_amdgcn_s_setprio(1);
        acc[4][0] = __builtin_amdgcn_mfma_f32_16x16x32_bf16(a4, b0, acc[4][0], 0, 0, 0);
        acc[4][1] = __builtin_amdgcn_mfma_f32_16x16x32_bf16(a4, b1, acc[4][1], 0, 0, 0);
        acc[4][2] = __builtin_amdgcn_mfma_f32_16x16x32_bf16(a4, b2, acc[4][2], 0, 0, 0);
        acc[4][3] = __builtin_amdgcn_mfma_f32_16x16x32_bf16(a4, b3, acc[4][3], 0, 0, 0);
        acc[5][0] = __builtin_amdgcn_mfma_f32_16x16x32_bf16(a5, b0, acc[5][0], 0, 0, 0);
        acc[5][1] = __builtin_amdgcn_mfma_f32_16x16x32_bf16(a5, b1, acc[5][1], 0, 0, 0);
        acc[5][2] = __builtin_amdgcn_mfma_f32_16x16x32_bf16(a5, b2, acc[5][2], 0, 0, 0);
        acc[5][3] = __builtin_amdgcn_mfma_f32_16x16x32_bf16(a5, b3, acc[5][3], 0, 0, 0);
        acc[6][0] = __builtin_amdgcn_mfma_f32_16x16x32_bf16(a6, b0, acc[6][0], 0, 0, 0);
        acc[6][1] = __builtin_amdgcn_mfma_f32_16x16x32_bf16(a6, b1, acc[6][1], 0, 0, 0);
        acc[6][2] = __builtin_amdgcn_mfma_f32_16x16x32_bf16(a6, b2, acc[6][2], 0, 0, 0);
        acc[6][3] = __builtin_amdgcn_mfma_f32_16x16x32_bf16(a6, b3, acc[6][3], 0, 0, 0);
        acc[7][0] = __builtin_amdgcn_mfma_f32_16x16x32_bf16(a7, b0, acc[7][0], 0, 0, 0);
        acc[7][1] = __builtin_amdgcn_mfma_f32_16x16x32_bf16(a7, b1, acc[7][1], 0, 0, 0);
        acc[7][2] = __builtin_amdgcn_mfma_f32_16x16x32_bf16(a7, b2, acc[7][2], 0, 0, 0);
        acc[7][3] = __builtin_amdgcn_mfma_f32_16x16x32_bf16(a7, b3, acc[7][3], 0, 0, 0);
        __builtin_amdgcn_s_setprio(0);

        // boundary: counted vmcnt (tile t+1 staged), never 0 in steady state
        if (t + 3 < NKT) {
            asm volatile("s_waitcnt vmcnt(8)" ::: "memory");
        } else if (t + 2 < NKT) {
            asm volatile("s_waitcnt vmcnt(4)" ::: "memory");
        } else if (t + 1 < NKT) {
            asm volatile("s_waitcnt vmcnt(0)" ::: "memory");
        }
        if (t + 1 < NKT) {
            __builtin_amdgcn_sched_barrier(0);
            __builtin_amdgcn_s_barrier();
            __builtin_amdgcn_sched_barrier(0);
        }
    }

    // ---- epilogue: dequant scale + bias, fp32 store ----
    const int cl = l & 15;
    const int rg = l >> 4;
    const size_t rowbase = (size_t)(bm * 256 + wr * 128);
#pragma unroll
    for (int fn = 0; fn < 4; ++fn) {
        const int col = bn * 256 + wc * 64 + fn * 16 + cl;
        const float sc = row_scales[col] * (1.0f / 127.0f);
        const float bs = bias[col];
#pragma unroll
        for (int fm = 0; fm < 8; ++fm) {
#pragma unroll
            for (int r = 0; r < 4; ++r) {
                const size_t row = rowbase + fm * 16 + rg * 4 + r;
                out[row * N_OUT + col] = acc[fm][fn][r] * sc + bs;
            }
        }
    }
}

// ---------------- launch ----------------

extern "C" void kernel_launch(void* const* d_in, const int* in_sizes, int n_in,
                              void* d_out, int out_size, void* d_ws, size_t ws_size,
                              hipStream_t stream) {
    const float* x = (const float*)d_in[0];
    const int* wq = (const int*)d_in[1];
    const float* row_scales = (const float*)d_in[2];
    const float* bias = (const float*)d_in[3];
    float* out = (float*)d_out;

    const size_t xbf_bytes = (size_t)M_TOK * K_IN * 2;  // 64 MiB

    unsigned short* xbf = (unsigned short*)d_ws;
    unsigned short* wbf = (unsigned short*)((char*)d_ws + xbf_bytes);
    (void)ws_size;

    cvt_x_kernel<<<2048, 256, 0, stream>>>(x, xbf);
    cvt_w_kernel<<<1024, 256, 0, stream>>>(wq, wbf);

    const int nblocks = (M_TOK / 256) * (N_OUT / 256);  // 512
    qgemm8_kernel<<<nblocks, 512, 0, stream>>>(xbf, wbf, row_scales, bias, out);
}

// Round 4
// 289.311 us; speedup vs baseline: 1.4455x; 1.0281x over previous
//
#include <hip/hip_runtime.h>

#define M_TOK 8192
#define N_OUT 4096
#define K_IN  4096

#define AS1 __attribute__((address_space(1)))
#define AS3 __attribute__((address_space(3)))

typedef __attribute__((ext_vector_type(8))) short bf16x8;
typedef __attribute__((ext_vector_type(16))) float f32x16;
typedef __attribute__((ext_vector_type(8))) unsigned short u16x8;

__device__ __forceinline__ unsigned short f2bf_rne(float f) {
    unsigned int u = __float_as_uint(f);
    u += 0x7fffu + ((u >> 16) & 1u);
    return (unsigned short)(u >> 16);
}

__device__ __forceinline__ unsigned short i2bf_exact(int v) {
    return (unsigned short)(__float_as_uint((float)v) >> 16);
}

// inline-asm ds_read_b128: invisible to compiler AA; ordering is OURS via
// counted lgkmcnt + sched_barrier(0) (rule 18).
template <int OFF>
__device__ __forceinline__ bf16x8 dsr(unsigned addr) {
    bf16x8 r;
    asm volatile("ds_read_b128 %0, %1 offset:%2" : "=v"(r) : "v"(addr), "n"(OFF));
    return r;
}

// ---------------- pre-convert kernels ----------------

__global__ void cvt_x_kernel(const float* __restrict__ x, unsigned short* __restrict__ o) {
    const int n8 = (M_TOK * K_IN) / 8;
    const int stride = gridDim.x * blockDim.x;
    for (int t = blockIdx.x * blockDim.x + threadIdx.x; t < n8; t += stride) {
        float4 a = reinterpret_cast<const float4*>(x)[2 * t];
        float4 b = reinterpret_cast<const float4*>(x)[2 * t + 1];
        u16x8 r;
        r[0] = f2bf_rne(a.x); r[1] = f2bf_rne(a.y);
        r[2] = f2bf_rne(a.z); r[3] = f2bf_rne(a.w);
        r[4] = f2bf_rne(b.x); r[5] = f2bf_rne(b.y);
        r[6] = f2bf_rne(b.z); r[7] = f2bf_rne(b.w);
        reinterpret_cast<u16x8*>(o)[t] = r;
    }
}

__global__ void cvt_w_kernel(const int* __restrict__ w, unsigned short* __restrict__ o) {
    const int n8 = (N_OUT * K_IN) / 8;
    const int stride = gridDim.x * blockDim.x;
    for (int t = blockIdx.x * blockDim.x + threadIdx.x; t < n8; t += stride) {
        int4 a = reinterpret_cast<const int4*>(w)[2 * t];
        int4 b = reinterpret_cast<const int4*>(w)[2 * t + 1];
        u16x8 r;
        r[0] = i2bf_exact(a.x); r[1] = i2bf_exact(a.y);
        r[2] = i2bf_exact(a.z); r[3] = i2bf_exact(a.w);
        r[4] = i2bf_exact(b.x); r[5] = i2bf_exact(b.y);
        r[6] = i2bf_exact(b.z); r[7] = i2bf_exact(b.w);
        reinterpret_cast<u16x8*>(o)[t] = r;
    }
}

// ------------- 256x256 GEMM, cross-tile reg pipeline, 32x32x16 MFMA -------------
// C[M,N] = Xbf[M,K] * Wbf[N,K]^T. BK=32 K-tiles, ring-4 LDS slots (128 KiB).
// 512 threads = 8 waves (2 wr x 4 wc); wave owns 128x64 = acc[4 mb][2 nb] of
// v_mfma_f32_32x32x16_bf16 (f32x16 acc each).
// Pipeline: tile t+1's 12 ds_reads are issued DURING tile t's MFMA clusters
// (double-buffered fragment regs c*/n*), so the LDS drain hides under MFMA.
// Waits: entry lgkm(4) (B+A.k0 ready), mid lgkm(8) (A.k1 ready);
// staging depth 3 (stage(t+3)), boundary vmcnt(4) -> slot t+2 confirmed for
// body t+1's reads. One barrier per tile.
// Swizzle: LDS granule' = g ^ ((row>>1)&3); staged via inverse-pre-swizzled
// global source (linear glds dest); ds_read k-step1 addr = k-step0 addr ^ 32.

#define BK 32
#define NKT (K_IN / BK)          // 128
#define SLOT_BYTES 16384         // 256 rows x 64 B
#define NSLOT 4

#define MFMA(a, b, c) c = __builtin_amdgcn_mfma_f32_32x32x16_bf16(a, b, c, 0, 0, 0)

// first 8 reads of a tile: B(nb0,k0) B(nb1,k0) B(nb0,k1) B(nb1,k1) A(mb0-3,k0)
#define RD8(P, aN0, aN1, bN0, bN1)                        \
    P##B0 = dsr<0>(bN0);    P##B1 = dsr<2048>(bN0);       \
    P##B2 = dsr<0>(bN1);    P##B3 = dsr<2048>(bN1);       \
    P##A0 = dsr<0>(aN0);    P##A1 = dsr<2048>(aN0);       \
    P##A2 = dsr<4096>(aN0); P##A3 = dsr<6144>(aN0);

// last 4 reads: A(mb0-3, k1)
#define RD4(P, aN1)                                       \
    P##A4 = dsr<0>(aN1);    P##A5 = dsr<2048>(aN1);       \
    P##A6 = dsr<4096>(aN1); P##A7 = dsr<6144>(aN1);

// steady-state body for tile T: compute set C (reads issued last body),
// issue set N's reads for tile T+1, stage tile T+3.
#define GBODY(T, C, N, DO_STAGE)                                          \
    {                                                                     \
        asm volatile("s_waitcnt lgkmcnt(4)" ::: "memory");                \
        __builtin_amdgcn_sched_barrier(0);                                \
        __builtin_amdgcn_s_setprio(1);                                    \
        MFMA(C##A0, C##B0, acc00); MFMA(C##A0, C##B1, acc01);             \
        MFMA(C##A1, C##B0, acc10); MFMA(C##A1, C##B1, acc11);             \
        MFMA(C##A2, C##B0, acc20); MFMA(C##A2, C##B1, acc21);             \
        MFMA(C##A3, C##B0, acc30); MFMA(C##A3, C##B1, acc31);             \
        __builtin_amdgcn_s_setprio(0);                                    \
        __builtin_amdgcn_sched_barrier(0);                                \
        const unsigned so_ = (unsigned)((((T) + 1) & 3) * SLOT_BYTES);    \
        const unsigned aN0 = aab0 + so_, aN1 = aab1 + so_;                \
        const unsigned bN0 = bbb0 + so_, bN1 = bbb1 + so_;                \
        RD8(N, aN0, aN1, bN0, bN1);                                       \
        if (DO_STAGE) { stageA((T) + 3); stageB((T) + 3); }               \
        asm volatile("s_waitcnt lgkmcnt(8)" ::: "memory");                \
        __builtin_amdgcn_sched_barrier(0);                                \
        __builtin_amdgcn_s_setprio(1);                                    \
        MFMA(C##A4, C##B2, acc00); MFMA(C##A4, C##B3, acc01);             \
        MFMA(C##A5, C##B2, acc10); MFMA(C##A5, C##B3, acc11);             \
        MFMA(C##A6, C##B2, acc20); MFMA(C##A6, C##B3, acc21);             \
        MFMA(C##A7, C##B2, acc30); MFMA(C##A7, C##B3, acc31);             \
        __builtin_amdgcn_s_setprio(0);                                    \
        __builtin_amdgcn_sched_barrier(0);                                \
        RD4(N, aN1);                                                      \
        asm volatile("s_waitcnt vmcnt(4)" ::: "memory");                  \
        __builtin_amdgcn_sched_barrier(0);                                \
        __builtin_amdgcn_s_barrier();                                     \
        __builtin_amdgcn_sched_barrier(0);                                \
    }

// last tile: compute only
#define GFINAL(C)                                                         \
    {                                                                     \
        asm volatile("s_waitcnt lgkmcnt(4)" ::: "memory");                \
        __builtin_amdgcn_sched_barrier(0);                                \
        __builtin_amdgcn_s_setprio(1);                                    \
        MFMA(C##A0, C##B0, acc00); MFMA(C##A0, C##B1, acc01);             \
        MFMA(C##A1, C##B0, acc10); MFMA(C##A1, C##B1, acc11);             \
        MFMA(C##A2, C##B0, acc20); MFMA(C##A2, C##B1, acc21);             \
        MFMA(C##A3, C##B0, acc30); MFMA(C##A3, C##B1, acc31);             \
        __builtin_amdgcn_s_setprio(0);                                    \
        asm volatile("s_waitcnt lgkmcnt(0)" ::: "memory");                \
        __builtin_amdgcn_sched_barrier(0);                                \
        __builtin_amdgcn_s_setprio(1);                                    \
        MFMA(C##A4, C##B2, acc00); MFMA(C##A4, C##B3, acc01);             \
        MFMA(C##A5, C##B2, acc10); MFMA(C##A5, C##B3, acc11);             \
        MFMA(C##A6, C##B2, acc20); MFMA(C##A6, C##B3, acc21);             \
        MFMA(C##A7, C##B2, acc30); MFMA(C##A7, C##B3, acc31);             \
        __builtin_amdgcn_s_setprio(0);                                    \
        __builtin_amdgcn_sched_barrier(0);                                \
    }

__global__ __launch_bounds__(512, 2) void qgemm9_kernel(
    const unsigned short* __restrict__ xbf,
    const unsigned short* __restrict__ wbf,
    const float* __restrict__ row_scales,
    const float* __restrict__ bias,
    float* __restrict__ out)
{
    __shared__ __align__(16) char smem[2 * NSLOT * SLOT_BYTES];  // A [0,64K), B [64K,128K)

    const int tid = threadIdx.x;
    const int l = tid & 63;
    const int w = tid >> 6;
    const int wr = w >> 2;   // 0..1
    const int wc = w & 3;    // 0..3

    // XCD-aware bijective swizzle (nwg = 512, 512 % 8 == 0)
    const int bid = blockIdx.x;
    const int swz = (bid & 7) * 64 + (bid >> 3);
    const int bm = swz >> 4;   // 0..31
    const int bn = swz & 15;   // 0..15

    // ---- staging addressing (linear LDS dest; pre-swizzled global src) ----
    const int rloc0 = tid >> 2;                       // row 0..127 (j adds 128)
    const int gs = (l & 3) ^ ((l >> 3) & 3);          // inverse-swizzled source granule
    const unsigned short* aSrc = xbf + (size_t)(bm * 256 + rloc0) * K_IN + gs * 8;
    const unsigned short* bSrc = wbf + (size_t)(bn * 256 + rloc0) * K_IN + gs * 8;
    char* aDst0 = smem + w * 1024;                    // wave-uniform; HW adds lane*16
    char* bDst0 = smem + NSLOT * SLOT_BYTES + w * 1024;

    auto stageA = [&](int tt) {
        const int sb = (tt & 3) * SLOT_BYTES;
#pragma unroll
        for (int j = 0; j < 2; ++j)
            __builtin_amdgcn_global_load_lds(
                (const AS1 void*)(aSrc + (size_t)j * 128 * K_IN + tt * BK),
                (AS3 void*)(aDst0 + sb + j * 8192), 16, 0, 0);
    };
    auto stageB = [&](int tt) {
        const int sb = (tt & 3) * SLOT_BYTES;
#pragma unroll
        for (int j = 0; j < 2; ++j)
            __builtin_amdgcn_global_load_lds(
                (const AS1 void*)(bSrc + (size_t)j * 128 * K_IN + tt * BK),
                (AS3 void*)(bDst0 + sb + j * 8192), 16, 0, 0);
    };

    // ---- fragment ds_read lane addresses (swizzled) ----
    // A frag (mb,ks): lane l -> row wr*128 + mb*32 + (l&31), logical granule
    // 2*ks + (l>>5); phys granule = logical ^ ((row>>1)&3) = logical ^ ((l>>1)&3).
    // ks=1 addr == ks=0 addr ^ 32 (granule bit1 flip).
    const unsigned sbase = (unsigned)(uintptr_t)(AS3 char*)smem;
    const int rr = l & 31;
    const unsigned g0 = (unsigned)((((l >> 5) ^ ((l >> 1) & 3))) << 4);
    const unsigned aab0 = sbase + (unsigned)((wr * 128 + rr) * 64) + g0;
    const unsigned aab1 = aab0 ^ 32u;
    const unsigned bbb0 = sbase + (unsigned)(NSLOT * SLOT_BYTES)
                                + (unsigned)((wc * 64 + rr) * 64) + g0;
    const unsigned bbb1 = bbb0 ^ 32u;

    // ---- accumulators: acc[mb][nb], f32x16 each ----
    f32x16 acc00 = {0}, acc01 = {0}, acc10 = {0}, acc11 = {0};
    f32x16 acc20 = {0}, acc21 = {0}, acc30 = {0}, acc31 = {0};

    // ---- fragment register sets ----
    bf16x8 cA0, cA1, cA2, cA3, cA4, cA5, cA6, cA7, cB0, cB1, cB2, cB3;
    bf16x8 nA0, nA1, nA2, nA3, nA4, nA5, nA6, nA7, nB0, nB1, nB2, nB3;

    // ---- prologue ----
    stageA(0); stageB(0);
    stageA(1); stageB(1);
    stageA(2); stageB(2);
    asm volatile("s_waitcnt vmcnt(4)" ::: "memory");   // slots 0,1 confirmed
    __builtin_amdgcn_sched_barrier(0);
    __builtin_amdgcn_s_barrier();
    __builtin_amdgcn_sched_barrier(0);
    {   // tile 0 reads into set c (slot 0)
        const unsigned aN0 = aab0, aN1 = aab1, bN0 = bbb0, bN1 = bbb1;
        RD8(c, aN0, aN1, bN0, bN1);
        RD4(c, aN1);
    }

    // ---- main loop: 2-tile unroll (sets c/n alternate) ----
    for (int t = 0; t < 126; t += 2) {
        GBODY(t, c, n, (t + 3 < NKT));
        GBODY(t + 1, n, c, (t + 4 < NKT));
    }
    GBODY(126, c, n, false);
    GFINAL(n);

    // ---- epilogue: dequant scale + bias, fp32 store ----
    // C/D 32x32 layout: col = nb*32 + (l&31); row = mb*32 + (reg&3) + 8*(reg>>2) + 4*(l>>5)
    const int cl = l & 31;
    const int rg4 = (l >> 5) * 4;
    const size_t row0 = (size_t)(bm * 256 + wr * 128);
    const int col0 = bn * 256 + wc * 64;

    const f32x16* accs[2][4] = {{&acc00, &acc10, &acc20, &acc30},
                                {&acc01, &acc11, &acc21, &acc31}};
#pragma unroll
    for (int nb = 0; nb < 2; ++nb) {
        const int col = col0 + nb * 32 + cl;
        const float sc = row_scales[col] * (1.0f / 127.0f);
        const float bs = bias[col];
#pragma unroll
        for (int mb = 0; mb < 4; ++mb) {
            const f32x16 a = *accs[nb][mb];
#pragma unroll
            for (int reg = 0; reg < 16; ++reg) {
                const size_t row = row0 + mb * 32 + (reg & 3) + 8 * (reg >> 2) + rg4;
                out[row * N_OUT + col] = a[reg] * sc + bs;
            }
        }
    }
}

// ---------------- launch ----------------

extern "C" void kernel_launch(void* const* d_in, const int* in_sizes, int n_in,
                              void* d_out, int out_size, void* d_ws, size_t ws_size,
                              hipStream_t stream) {
    const float* x = (const float*)d_in[0];
    const int* wq = (const int*)d_in[1];
    const float* row_scales = (const float*)d_in[2];
    const float* bias = (const float*)d_in[3];
    float* out = (float*)d_out;

    const size_t xbf_bytes = (size_t)M_TOK * K_IN * 2;  // 64 MiB

    unsigned short* xbf = (unsigned short*)d_ws;
    unsigned short* wbf = (unsigned short*)((char*)d_ws + xbf_bytes);
    (void)ws_size;

    cvt_x_kernel<<<2048, 256, 0, stream>>>(x, xbf);
    cvt_w_kernel<<<1024, 256, 0, stream>>>(wq, wbf);

    const int nblocks = (M_TOK / 256) * (N_OUT / 256);  // 512
    qgemm9_kernel<<<nblocks, 512, 0, stream>>>(xbf, wbf, row_scales, bias, out);
}

// Round 5
// 265.563 us; speedup vs baseline: 1.5747x; 1.0894x over previous
//
#include <hip/hip_runtime.h>

#define M_TOK 8192
#define N_OUT 4096
#define K_IN  4096

#define AS1 __attribute__((address_space(1)))
#define AS3 __attribute__((address_space(3)))

typedef __attribute__((ext_vector_type(4))) int i32x4;
typedef __attribute__((ext_vector_type(16))) int i32x16;

// inline-asm ds_read_b128: invisible to compiler AA; ordering is OURS via
// counted lgkmcnt + sched_barrier(0) (rule 18).
template <int OFF>
__device__ __forceinline__ i32x4 dsri(unsigned addr) {
    i32x4 r;
    asm volatile("ds_read_b128 %0, %1 offset:%2" : "=v"(r) : "v"(addr), "n"(OFF));
    return r;
}

// ---------------- prepass 1: per-token absmax quant of x ----------------
// one block per token row; 4096 f32 -> 4096 i8 + tok_scale[row] = absmax/127

__global__ __launch_bounds__(256) void quant_x_kernel(
    const float* __restrict__ x, signed char* __restrict__ xq,
    float* __restrict__ tok_scale)
{
    const int row = blockIdx.x;
    const float4* xr = reinterpret_cast<const float4*>(x + (size_t)row * K_IN);
    const int t = threadIdx.x;
    float4 v[4];
    float m = 0.f;
#pragma unroll
    for (int i = 0; i < 4; ++i) {
        v[i] = xr[t + 256 * i];
        m = fmaxf(m, fmaxf(fmaxf(fabsf(v[i].x), fabsf(v[i].y)),
                           fmaxf(fabsf(v[i].z), fabsf(v[i].w))));
    }
#pragma unroll
    for (int off = 32; off >= 1; off >>= 1)
        m = fmaxf(m, __shfl_xor(m, off, 64));
    __shared__ float wmax[4];
    if ((t & 63) == 0) wmax[t >> 6] = m;
    __syncthreads();
    m = fmaxf(fmaxf(wmax[0], wmax[1]), fmaxf(wmax[2], wmax[3]));
    if (t == 0) tok_scale[row] = m * (1.0f / 127.0f);
    const float inv = (m > 0.f) ? (127.0f / m) : 0.f;
    int* xqi = reinterpret_cast<int*>(xq + (size_t)row * K_IN);
#pragma unroll
    for (int i = 0; i < 4; ++i) {
        const int q0 = __float2int_rn(v[i].x * inv) & 255;
        const int q1 = __float2int_rn(v[i].y * inv) & 255;
        const int q2 = __float2int_rn(v[i].z * inv) & 255;
        const int q3 = __float2int_rn(v[i].w * inv) & 255;
        xqi[t + 256 * i] = q0 | (q1 << 8) | (q2 << 16) | (q3 << 24);
    }
}

// ---------------- prepass 2: pack Wq int32 -> int8 ----------------

__global__ void pack_w_kernel(const int* __restrict__ wq, signed char* __restrict__ o) {
    const int n4 = (N_OUT * K_IN) / 4;
    int* o4 = reinterpret_cast<int*>(o);
    const int stride = gridDim.x * blockDim.x;
    for (int i = blockIdx.x * blockDim.x + threadIdx.x; i < n4; i += stride) {
        const int4 a = reinterpret_cast<const int4*>(wq)[i];
        o4[i] = (a.x & 255) | ((a.y & 255) << 8) | ((a.z & 255) << 16) | ((a.w & 255) << 24);
    }
}

// ---------------- int8 GEMM: 256x128 tile, 4 waves (2x2), mfma_i32_32x32x32_i8 ----
// C = Xq[M,K] * Wq8[N,K]^T (i32 acc), epilogue: out = acc*ts[row]*(rs[col]/127)+bias.
// BK=32 i8 (32B rows), ring-4 LDS slots: A 4x8KB, B 4x4KB, +1KB ts = 49.25KB
// -> 2 blocks/CU co-resident (inter-block latency hiding).
// Wave (wr,wc) owns 128x64 = acc[4 mb][2 nb] (i32x16 each). Read amp: A 2x, B 2x.
// Per K-tile: entry lgkm(2) -> 4 MFMA; issue next tile's 6 ds_reads + stage(t+3)
// (3 glds); lgkm(6) -> 4 MFMA; boundary vmcnt(3) (vmcnt(0) once staging ends);
// one barrier. Reads of tile T+1 are protected by body T-1's boundary (confirms
// through tile T+1).
// Bank swizzle (32B rows, 2 granules/row): phys_g = g ^ ((row>>2)&1); applied as
// inverse-pre-swizzled GLOBAL source (linear glds dest) + swizzled ds_read addr.

#define BKB 32
#define NKT (K_IN / BKB)   // 128
#define ASLOT 8192         // 256 rows x 32 B
#define BSLOT 4096         // 128 rows x 32 B

#define MFMA(a, b, c) c = __builtin_amdgcn_mfma_i32_32x32x32_i8(a, b, c, 0, 0, 0)

// 6 reads, fixed order: B0,B1,A0,A1 (cluster1 needs these), then A2,A3
#define RD6(P, aA, bA)                                   \
    P##B0 = dsri<0>(bA);    P##B1 = dsri<1024>(bA);      \
    P##A0 = dsri<0>(aA);    P##A1 = dsri<1024>(aA);      \
    P##A2 = dsri<2048>(aA); P##A3 = dsri<3072>(aA);

#define GBODY(T, C, N, DO_STAGE)                                          \
    {                                                                     \
        asm volatile("s_waitcnt lgkmcnt(2)" ::: "memory");                \
        __builtin_amdgcn_sched_barrier(0);                                \
        __builtin_amdgcn_s_setprio(1);                                    \
        MFMA(C##A0, C##B0, acc00); MFMA(C##A0, C##B1, acc01);             \
        MFMA(C##A1, C##B0, acc10); MFMA(C##A1, C##B1, acc11);             \
        __builtin_amdgcn_s_setprio(0);                                    \
        __builtin_amdgcn_sched_barrier(0);                                \
        const unsigned so_ = (unsigned)(((T) + 1) & 3);                   \
        const unsigned aN = aab + so_ * ASLOT;                            \
        const unsigned bN = bbb + so_ * BSLOT;                            \
        RD6(N, aN, bN);                                                   \
        if (DO_STAGE) { stageA((T) + 3); stageB((T) + 3); }               \
        asm volatile("s_waitcnt lgkmcnt(6)" ::: "memory");                \
        __builtin_amdgcn_sched_barrier(0);                                \
        __builtin_amdgcn_s_setprio(1);                                    \
        MFMA(C##A2, C##B0, acc20); MFMA(C##A2, C##B1, acc21);             \
        MFMA(C##A3, C##B0, acc30); MFMA(C##A3, C##B1, acc31);             \
        __builtin_amdgcn_s_setprio(0);                                    \
        __builtin_amdgcn_sched_barrier(0);                                \
        if (DO_STAGE) { asm volatile("s_waitcnt vmcnt(3)" ::: "memory"); }\
        else          { asm volatile("s_waitcnt vmcnt(0)" ::: "memory"); }\
        __builtin_amdgcn_sched_barrier(0);                                \
        __builtin_amdgcn_s_barrier();                                     \
        __builtin_amdgcn_sched_barrier(0);                                \
    }

#define GFINAL(C)                                                         \
    {                                                                     \
        asm volatile("s_waitcnt lgkmcnt(2)" ::: "memory");                \
        __builtin_amdgcn_sched_barrier(0);                                \
        __builtin_amdgcn_s_setprio(1);                                    \
        MFMA(C##A0, C##B0, acc00); MFMA(C##A0, C##B1, acc01);             \
        MFMA(C##A1, C##B0, acc10); MFMA(C##A1, C##B1, acc11);             \
        __builtin_amdgcn_s_setprio(0);                                    \
        asm volatile("s_waitcnt lgkmcnt(0)" ::: "memory");                \
        __builtin_amdgcn_sched_barrier(0);                                \
        __builtin_amdgcn_s_setprio(1);                                    \
        MFMA(C##A2, C##B0, acc20); MFMA(C##A2, C##B1, acc21);             \
        MFMA(C##A3, C##B0, acc30); MFMA(C##A3, C##B1, acc31);             \
        __builtin_amdgcn_s_setprio(0);                                    \
        __builtin_amdgcn_sched_barrier(0);                                \
    }

__global__ __launch_bounds__(256, 2) void qgemm_i8_kernel(
    const signed char* __restrict__ xq,
    const signed char* __restrict__ wq8,
    const float* __restrict__ tok_scale,
    const float* __restrict__ row_scales,
    const float* __restrict__ bias,
    float* __restrict__ out)
{
    __shared__ __align__(16) char smem[4 * ASLOT + 4 * BSLOT + 1024];
    // A slots [0,32K), B slots [32K,48K), ts [48K,49K)

    const int tid = threadIdx.x;
    const int l = tid & 63;
    const int w = tid >> 6;      // 0..3
    const int wr = w >> 1;       // 0..1
    const int wc = w & 1;        // 0..1

    // XCD-aware bijective swizzle (nwg = 1024, 1024 % 8 == 0)
    const int bid = blockIdx.x;
    const int swz = (bid & 7) * 128 + (bid >> 3);
    const int bm = swz >> 5;     // 0..31
    const int bn = swz & 31;     // 0..31

    // ---- staging (linear glds dest; inverse-pre-swizzled global src) ----
    // dest row = [j*128 +] w*32 + (l>>1), dest granule = l&1;
    // src granule = (l&1) ^ ((row>>2)&1) = (l&1) ^ ((l>>3)&1)
    const int gsrc = (l & 1) ^ ((l >> 3) & 1);
    const signed char* aS = xq  + (size_t)(bm * 256 + w * 32 + (l >> 1)) * K_IN + gsrc * 16;
    const signed char* bS = wq8 + (size_t)(bn * 128 + w * 32 + (l >> 1)) * K_IN + gsrc * 16;
    char* aD = smem + w * 1024;
    char* bD = smem + 4 * ASLOT + w * 1024;

    auto stageA = [&](int tt) {
        const int sb = (tt & 3) * ASLOT;
#pragma unroll
        for (int j = 0; j < 2; ++j)
            __builtin_amdgcn_global_load_lds(
                (const AS1 void*)(aS + (size_t)j * 128 * K_IN + tt * BKB),
                (AS3 void*)(aD + sb + j * 4096), 16, 0, 0);
    };
    auto stageB = [&](int tt) {
        const int sb = (tt & 3) * BSLOT;
        __builtin_amdgcn_global_load_lds(
            (const AS1 void*)(bS + tt * BKB),
            (AS3 void*)(bD + sb), 16, 0, 0);
    };

    // ---- fragment ds_read addrs (swizzled) ----
    // lane l: row base + (l&31), logical granule l>>5, phys = (l>>5)^((l>>2)&1)
    const unsigned sbase = (unsigned)(uintptr_t)(AS3 char*)smem;
    const int rr = l & 31;
    const unsigned gph = (unsigned)((((l >> 5) ^ ((l >> 2) & 1))) << 4);
    const unsigned aab = sbase + (unsigned)((wr * 128 + rr) * 32) + gph;              // + slot*ASLOT + mb*1024
    const unsigned bbb = sbase + (unsigned)(4 * ASLOT) + (unsigned)((wc * 64 + rr) * 32) + gph;  // + slot*BSLOT + nb*1024

    i32x16 acc00 = {0}, acc01 = {0}, acc10 = {0}, acc11 = {0};
    i32x16 acc20 = {0}, acc21 = {0}, acc30 = {0}, acc31 = {0};

    i32x4 cA0, cA1, cA2, cA3, cB0, cB1;
    i32x4 nA0, nA1, nA2, nA3, nB0, nB1;

    // ---- prologue: stage tiles 0,1,2 (9 glds); vmcnt(3) confirms tiles 0,1 ----
    stageA(0); stageB(0);
    stageA(1); stageB(1);
    stageA(2); stageB(2);
    asm volatile("s_waitcnt vmcnt(3)" ::: "memory");
    __builtin_amdgcn_sched_barrier(0);
    __builtin_amdgcn_s_barrier();
    __builtin_amdgcn_sched_barrier(0);
    RD6(c, aab, bbb);   // tile 0 (slot 0)

    // ---- main loop ----
    for (int t = 0; t < 126; t += 2) {
        GBODY(t, c, n, (t + 3 < NKT));
        GBODY(t + 1, n, c, (t + 4 < NKT));
    }
    GBODY(126, c, n, false);
    GFINAL(n);

    // ---- epilogue: stage tok_scales, dequant, store ----
    float* ts = (float*)(smem + 4 * ASLOT + 4 * BSLOT);
    ts[tid] = tok_scale[bm * 256 + tid];
    __syncthreads();

    const int cl = l & 31;
    const int rg4 = (l >> 5) * 4;
    const int gcol0 = bn * 128 + wc * 64;
    float cs[2], bb[2];
#pragma unroll
    for (int nb = 0; nb < 2; ++nb) {
        const int col = gcol0 + nb * 32 + cl;
        cs[nb] = row_scales[col] * (1.0f / 127.0f);
        bb[nb] = bias[col];
    }
    const i32x16* accs[4][2] = {{&acc00, &acc01}, {&acc10, &acc11},
                                {&acc20, &acc21}, {&acc30, &acc31}};
#pragma unroll
    for (int mb = 0; mb < 4; ++mb) {
#pragma unroll
        for (int reg = 0; reg < 16; ++reg) {
            const int rloc = wr * 128 + mb * 32 + (reg & 3) + 8 * (reg >> 2) + rg4;
            const float tsv = ts[rloc];
            float* orow = out + (size_t)(bm * 256 + rloc) * N_OUT + gcol0 + cl;
#pragma unroll
            for (int nb = 0; nb < 2; ++nb) {
                const int a = (*accs[mb][nb])[reg];
                orow[nb * 32] = (float)a * tsv * cs[nb] + bb[nb];
            }
        }
    }
}

// ---------------- launch ----------------

extern "C" void kernel_launch(void* const* d_in, const int* in_sizes, int n_in,
                              void* d_out, int out_size, void* d_ws, size_t ws_size,
                              hipStream_t stream) {
    const float* x = (const float*)d_in[0];
    const int* wq = (const int*)d_in[1];
    const float* row_scales = (const float*)d_in[2];
    const float* bias = (const float*)d_in[3];
    float* out = (float*)d_out;

    signed char* xq8 = (signed char*)d_ws;                       // 32 MiB
    signed char* wq8 = xq8 + (size_t)M_TOK * K_IN;               // 16 MiB
    float* tok_scale = (float*)(wq8 + (size_t)N_OUT * K_IN);     // 32 KiB
    (void)ws_size;

    quant_x_kernel<<<M_TOK, 256, 0, stream>>>(x, xq8, tok_scale);
    pack_w_kernel<<<2048, 256, 0, stream>>>(wq, wq8);

    const int nblocks = (M_TOK / 256) * (N_OUT / 128);  // 1024
    qgemm_i8_kernel<<<nblocks, 256, 0, stream>>>(
        xq8, wq8, tok_scale, row_scales, bias, out);
}

// Round 7
// 212.808 us; speedup vs baseline: 1.9651x; 1.2479x over previous
//
#include <hip/hip_runtime.h>

#define M_TOK 8192
#define N_OUT 4096
#define K_IN  4096

#define AS1 __attribute__((address_space(1)))
#define AS3 __attribute__((address_space(3)))

typedef __attribute__((ext_vector_type(4))) int i32x4;
typedef __attribute__((ext_vector_type(16))) int i32x16;

// inline-asm ds_read_b128: invisible to compiler AA; ordering is OURS via
// counted lgkmcnt + sched_barrier(0) (rule 18).
template <int OFF>
__device__ __forceinline__ i32x4 dsri(unsigned addr) {
    i32x4 r;
    asm volatile("ds_read_b128 %0, %1 offset:%2" : "=v"(r) : "v"(addr), "n"(OFF));
    return r;
}

// ---------------- prepass 1: per-token absmax quant of x ----------------

__global__ __launch_bounds__(256) void quant_x_kernel(
    const float* __restrict__ x, signed char* __restrict__ xq,
    float* __restrict__ tok_scale)
{
    const int row = blockIdx.x;
    const float4* xr = reinterpret_cast<const float4*>(x + (size_t)row * K_IN);
    const int t = threadIdx.x;
    float4 v[4];
    float m = 0.f;
#pragma unroll
    for (int i = 0; i < 4; ++i) {
        v[i] = xr[t + 256 * i];
        m = fmaxf(m, fmaxf(fmaxf(fabsf(v[i].x), fabsf(v[i].y)),
                           fmaxf(fabsf(v[i].z), fabsf(v[i].w))));
    }
#pragma unroll
    for (int off = 32; off >= 1; off >>= 1)
        m = fmaxf(m, __shfl_xor(m, off, 64));
    __shared__ float wmax[4];
    if ((t & 63) == 0) wmax[t >> 6] = m;
    __syncthreads();
    m = fmaxf(fmaxf(wmax[0], wmax[1]), fmaxf(wmax[2], wmax[3]));
    if (t == 0) tok_scale[row] = m * (1.0f / 127.0f);
    const float inv = (m > 0.f) ? (127.0f / m) : 0.f;
    int* xqi = reinterpret_cast<int*>(xq + (size_t)row * K_IN);
#pragma unroll
    for (int i = 0; i < 4; ++i) {
        const int q0 = __float2int_rn(v[i].x * inv) & 255;
        const int q1 = __float2int_rn(v[i].y * inv) & 255;
        const int q2 = __float2int_rn(v[i].z * inv) & 255;
        const int q3 = __float2int_rn(v[i].w * inv) & 255;
        xqi[t + 256 * i] = q0 | (q1 << 8) | (q2 << 16) | (q3 << 24);
    }
}

// ---------------- prepass 2: pack Wq int32 -> int8 ----------------

__global__ void pack_w_kernel(const int* __restrict__ wq, signed char* __restrict__ o) {
    const int n4 = (N_OUT * K_IN) / 4;
    int* o4 = reinterpret_cast<int*>(o);
    const int stride = gridDim.x * blockDim.x;
    for (int i = blockIdx.x * blockDim.x + threadIdx.x; i < n4; i += stride) {
        const int4 a = reinterpret_cast<const int4*>(wq)[i];
        o4[i] = (a.x & 255) | ((a.y & 255) << 8) | ((a.z & 255) << 16) | ((a.w & 255) << 24);
    }
}

// ------- int8 GEMM: 256x256 tile, BK=64, 8 waves, mfma_i32_32x32x32_i8 -------
// C = Xq[M,K]*Wq8[N,K]^T (i32 acc); out = acc*ts[row]*(rs[col]/127)+bias.
// FRAGMENT-LINEAR LDS: each MFMA fragment (32 rows x 32 K i8, R5-HW-verified
// lane map: row=l&31, kseg=(l>>5)*16) stored as contiguous 1KB; all ds_reads
// are base+lane*16 -> ZERO bank conflicts by construction; glds dest linear,
// global source is the per-lane fragment gather.
// Slot (32KB) = A frags [16x1KB] + B frags [16x1KB]; ring-4 = 128KB + 1KB ts.
// Per tile: 16 MFMA/wave (mb4 x nb2 x kh2), 12 ds_reads/wave, 4 glds/wave.
// Body: lgkm(0)->8 MFMA(kh0); read c2(kh1)+stage(t+3)+read n1(t+1,kh0);
// lgkm(6)->8 MFMA(kh1); boundary vmcnt(4) (confirms slot t+2, one body
// BEFORE its reads -> race-free); one barrier.
// 3-set frag rotation (sA, sB, sC) period 3.

#define BKB 64
#define NKT (K_IN / BKB)   // 64
#define SLOT 32768
#define NSLOT 4

#define MFMA(a, b, c) c = __builtin_amdgcn_mfma_i32_32x32x32_i8(a, b, c, 0, 0, 0)

#define RD6(P, aB, bB, KH)                         \
    P##_A0 = dsri<(0 * 2 + KH) * 1024>(aB);        \
    P##_A1 = dsri<(1 * 2 + KH) * 1024>(aB);        \
    P##_A2 = dsri<(2 * 2 + KH) * 1024>(aB);        \
    P##_A3 = dsri<(3 * 2 + KH) * 1024>(aB);        \
    P##_B0 = dsri<(0 * 2 + KH) * 1024>(bB);        \
    P##_B1 = dsri<(1 * 2 + KH) * 1024>(bB);

#define CL8(P)                                                \
    MFMA(P##_A0, P##_B0, acc00); MFMA(P##_A0, P##_B1, acc01); \
    MFMA(P##_A1, P##_B0, acc10); MFMA(P##_A1, P##_B1, acc11); \
    MFMA(P##_A2, P##_B0, acc20); MFMA(P##_A2, P##_B1, acc21); \
    MFMA(P##_A3, P##_B0, acc30); MFMA(P##_A3, P##_B1, acc31);

#define GBODY(T, C1, C2, N1, DO_STAGE)                                    \
    {                                                                     \
        asm volatile("s_waitcnt lgkmcnt(0)" ::: "memory");                \
        __builtin_amdgcn_sched_barrier(0);                                \
        __builtin_amdgcn_s_setprio(1);                                    \
        CL8(C1)                                                           \
        __builtin_amdgcn_s_setprio(0);                                    \
        __builtin_amdgcn_sched_barrier(0);                                \
        const unsigned aC_ = aBase + (unsigned)(((T) & 3) * SLOT);        \
        const unsigned bC_ = bBase + (unsigned)(((T) & 3) * SLOT);        \
        RD6(C2, aC_, bC_, 1)                                              \
        if (DO_STAGE) stageAB((T) + 3);                                   \
        const unsigned aN_ = aBase + (unsigned)((((T) + 1) & 3) * SLOT);  \
        const unsigned bN_ = bBase + (unsigned)((((T) + 1) & 3) * SLOT);  \
        RD6(N1, aN_, bN_, 0)                                              \
        asm volatile("s_waitcnt lgkmcnt(6)" ::: "memory");                \
        __builtin_amdgcn_sched_barrier(0);                                \
        __builtin_amdgcn_s_setprio(1);                                    \
        CL8(C2)                                                           \
        __builtin_amdgcn_s_setprio(0);                                    \
        __builtin_amdgcn_sched_barrier(0);                                \
        if (DO_STAGE) { asm volatile("s_waitcnt vmcnt(4)" ::: "memory"); }\
        else          { asm volatile("s_waitcnt vmcnt(0)" ::: "memory"); }\
        __builtin_amdgcn_sched_barrier(0);                                \
        __builtin_amdgcn_s_barrier();                                     \
        __builtin_amdgcn_sched_barrier(0);                                \
    }

#define GFINAL(C1, SC)                                                    \
    {                                                                     \
        asm volatile("s_waitcnt lgkmcnt(0)" ::: "memory");                \
        __builtin_amdgcn_sched_barrier(0);                                \
        __builtin_amdgcn_s_setprio(1);                                    \
        CL8(C1)                                                           \
        __builtin_amdgcn_s_setprio(0);                                    \
        __builtin_amdgcn_sched_barrier(0);                                \
        const unsigned aC_ = aBase + (unsigned)((63 & 3) * SLOT);         \
        const unsigned bC_ = bBase + (unsigned)((63 & 3) * SLOT);         \
        RD6(SC, aC_, bC_, 1)                                              \
        asm volatile("s_waitcnt lgkmcnt(0)" ::: "memory");                \
        __builtin_amdgcn_sched_barrier(0);                                \
        __builtin_amdgcn_s_setprio(1);                                    \
        CL8(SC)                                                           \
        __builtin_amdgcn_s_setprio(0);                                    \
        __builtin_amdgcn_sched_barrier(0);                                \
    }

__global__ __launch_bounds__(512, 2) void qgemm_i8k64_kernel(
    const signed char* __restrict__ xq,
    const signed char* __restrict__ wq8,
    const float* __restrict__ tok_scale,
    const float* __restrict__ row_scales,
    const float* __restrict__ bias,
    float* __restrict__ out)
{
    __shared__ __align__(16) char smem[NSLOT * SLOT + 1024];  // 129 KiB

    const int tid = threadIdx.x;
    const int l = tid & 63;
    const int w = tid >> 6;      // 0..7
    const int wr = w >> 2;       // 0..1
    const int wc = w & 3;        // 0..3

    // XCD-aware bijective swizzle (nwg = 512, 512 % 8 == 0)
    const int bid = blockIdx.x;
    const int swz = (bid & 7) * 64 + (bid >> 3);
    const int bm = swz >> 4;     // 0..31
    const int bn = swz & 15;     // 0..15

    // ---- staging: wave w owns A frags {2w,2w+1} and B frags {2w,2w+1} ----
    // frag f = fb*2 + kh; lane l supplies row fb*32+(l&31), kseg (l>>5)*16.
    const signed char* aS = xq  + (size_t)(bm * 256 + w * 32 + (l & 31)) * K_IN + (l >> 5) * 16;
    const signed char* bS = wq8 + (size_t)(bn * 256 + w * 32 + (l & 31)) * K_IN + (l >> 5) * 16;
    char* aDst = smem + w * 2048;              // A region [0,16K) of slot
    char* bDst = smem + 16384 + w * 2048;      // B region [16K,32K) of slot

    auto stageAB = [&](int tt) {
        const int sb = (tt & 3) * SLOT;
        const signed char* a0 = aS + tt * BKB;
        const signed char* b0 = bS + tt * BKB;
        __builtin_amdgcn_global_load_lds((const AS1 void*)a0,        (AS3 void*)(aDst + sb),        16, 0, 0);
        __builtin_amdgcn_global_load_lds((const AS1 void*)(a0 + 32), (AS3 void*)(aDst + sb + 1024), 16, 0, 0);
        __builtin_amdgcn_global_load_lds((const AS1 void*)b0,        (AS3 void*)(bDst + sb),        16, 0, 0);
        __builtin_amdgcn_global_load_lds((const AS1 void*)(b0 + 32), (AS3 void*)(bDst + sb + 1024), 16, 0, 0);
    };

    // ---- fragment-linear ds_read bases (+ compile-time frag offsets) ----
    const unsigned sbase = (unsigned)(uintptr_t)(AS3 char*)smem;
    const unsigned aBase = sbase + (unsigned)(wr * 8192 + l * 16);           // + slot + (mb*2+kh)*1024
    const unsigned bBase = sbase + 16384u + (unsigned)(wc * 4096 + l * 16);  // + slot + (nb*2+kh)*1024

    i32x16 acc00 = {0}, acc01 = {0}, acc10 = {0}, acc11 = {0};
    i32x16 acc20 = {0}, acc21 = {0}, acc30 = {0}, acc31 = {0};

    i32x4 sA_A0, sA_A1, sA_A2, sA_A3, sA_B0, sA_B1;
    i32x4 sB_A0, sB_A1, sB_A2, sB_A3, sB_B0, sB_B1;
    i32x4 sC_A0, sC_A1, sC_A2, sC_A3, sC_B0, sC_B1;

    // ---- prologue: stage tiles 0,1,2; confirm 0,1; read tile0 kh0 ----
    stageAB(0); stageAB(1); stageAB(2);
    asm volatile("s_waitcnt vmcnt(4)" ::: "memory");
    __builtin_amdgcn_sched_barrier(0);
    __builtin_amdgcn_s_barrier();
    __builtin_amdgcn_sched_barrier(0);
    RD6(sA, aBase, bBase, 0)

    // ---- main loop: bodies 0..62, 3-set rotation; body 63 = final ----
    for (int t = 0; t < 63; t += 3) {
        GBODY(t,     sA, sB, sC, (t + 3 < NKT));
        GBODY(t + 1, sC, sA, sB, (t + 4 < NKT));
        GBODY(t + 2, sB, sC, sA, (t + 5 < NKT));
    }
    GFINAL(sA, sB)

    // ---- epilogue: tok scales via LDS, dequant, store ----
    float* ts = (float*)(smem + NSLOT * SLOT);
    if (tid < 256) ts[tid] = tok_scale[bm * 256 + tid];
    __syncthreads();

    const int cl = l & 31;
    const int rg4 = (l >> 5) * 4;
    const int gcol0 = bn * 256 + wc * 64;
    float cs[2], bb[2];
#pragma unroll
    for (int nb = 0; nb < 2; ++nb) {
        const int col = gcol0 + nb * 32 + cl;
        cs[nb] = row_scales[col] * (1.0f / 127.0f);
        bb[nb] = bias[col];
    }
    const i32x16* accs[4][2] = {{&acc00, &acc01}, {&acc10, &acc11},
                                {&acc20, &acc21}, {&acc30, &acc31}};
#pragma unroll
    for (int mb = 0; mb < 4; ++mb) {
#pragma unroll
        for (int reg = 0; reg < 16; ++reg) {
            const int rloc = wr * 128 + mb * 32 + (reg & 3) + 8 * (reg >> 2) + rg4;
            const float tsv = ts[rloc];
            float* orow = out + (size_t)(bm * 256 + rloc) * N_OUT + gcol0 + cl;
#pragma unroll
            for (int nb = 0; nb < 2; ++nb) {
                const int a = (*accs[mb][nb])[reg];
                orow[nb * 32] = (float)a * tsv * cs[nb] + bb[nb];
            }
        }
    }
}

// ---------------- launch ----------------

extern "C" void kernel_launch(void* const* d_in, const int* in_sizes, int n_in,
                              void* d_out, int out_size, void* d_ws, size_t ws_size,
                              hipStream_t stream) {
    const float* x = (const float*)d_in[0];
    const int* wq = (const int*)d_in[1];
    const float* row_scales = (const float*)d_in[2];
    const float* bias = (const float*)d_in[3];
    float* out = (float*)d_out;

    signed char* xq8 = (signed char*)d_ws;                       // 32 MiB
    signed char* wq8 = xq8 + (size_t)M_TOK * K_IN;               // 16 MiB
    float* tok_scale = (float*)(wq8 + (size_t)N_OUT * K_IN);     // 32 KiB
    (void)ws_size;

    quant_x_kernel<<<M_TOK, 256, 0, stream>>>(x, xq8, tok_scale);
    pack_w_kernel<<<2048, 256, 0, stream>>>(wq, wq8);

    const int nblocks = (M_TOK / 256) * (N_OUT / 256);  // 512
    qgemm_i8k64_kernel<<<nblocks, 512, 0, stream>>>(
        xq8, wq8, tok_scale, row_scales, bias, out);
}

// Round 8
// 210.482 us; speedup vs baseline: 1.9868x; 1.0110x over previous
//
#include <hip/hip_runtime.h>

#define M_TOK 8192
#define N_OUT 4096
#define K_IN  4096

#define AS1 __attribute__((address_space(1)))
#define AS3 __attribute__((address_space(3)))

typedef __attribute__((ext_vector_type(4))) int i32x4;
typedef __attribute__((ext_vector_type(16))) int i32x16;

// inline-asm ds_read_b128: invisible to compiler AA; ordering is OURS via
// counted lgkmcnt + sched_barrier(0) (rule 18).
template <int OFF>
__device__ __forceinline__ i32x4 dsri(unsigned addr) {
    i32x4 r;
    asm volatile("ds_read_b128 %0, %1 offset:%2" : "=v"(r) : "v"(addr), "n"(OFF));
    return r;
}

// ---------------- prepass 1: per-token absmax quant of x ----------------

__global__ __launch_bounds__(256) void quant_x_kernel(
    const float* __restrict__ x, signed char* __restrict__ xq,
    float* __restrict__ tok_scale)
{
    const int row = blockIdx.x;
    const float4* xr = reinterpret_cast<const float4*>(x + (size_t)row * K_IN);
    const int t = threadIdx.x;
    float4 v[4];
    float m = 0.f;
#pragma unroll
    for (int i = 0; i < 4; ++i) {
        v[i] = xr[t + 256 * i];
        m = fmaxf(m, fmaxf(fmaxf(fabsf(v[i].x), fabsf(v[i].y)),
                           fmaxf(fabsf(v[i].z), fabsf(v[i].w))));
    }
#pragma unroll
    for (int off = 32; off >= 1; off >>= 1)
        m = fmaxf(m, __shfl_xor(m, off, 64));
    __shared__ float wmax[4];
    if ((t & 63) == 0) wmax[t >> 6] = m;
    __syncthreads();
    m = fmaxf(fmaxf(wmax[0], wmax[1]), fmaxf(wmax[2], wmax[3]));
    if (t == 0) tok_scale[row] = m * (1.0f / 127.0f);
    const float inv = (m > 0.f) ? (127.0f / m) : 0.f;
    int* xqi = reinterpret_cast<int*>(xq + (size_t)row * K_IN);
#pragma unroll
    for (int i = 0; i < 4; ++i) {
        const int q0 = __float2int_rn(v[i].x * inv) & 255;
        const int q1 = __float2int_rn(v[i].y * inv) & 255;
        const int q2 = __float2int_rn(v[i].z * inv) & 255;
        const int q3 = __float2int_rn(v[i].w * inv) & 255;
        xqi[t + 256 * i] = q0 | (q1 << 8) | (q2 << 16) | (q3 << 24);
    }
}

// ---------------- prepass 2: pack Wq int32 -> int8 ----------------

__global__ void pack_w_kernel(const int* __restrict__ wq, signed char* __restrict__ o) {
    const int n4 = (N_OUT * K_IN) / 4;
    int* o4 = reinterpret_cast<int*>(o);
    const int stride = gridDim.x * blockDim.x;
    for (int i = blockIdx.x * blockDim.x + threadIdx.x; i < n4; i += stride) {
        const int4 a = reinterpret_cast<const int4*>(wq)[i];
        o4[i] = (a.x & 255) | ((a.y & 255) << 8) | ((a.z & 255) << 16) | ((a.w & 255) << 24);
    }
}

// ------- int8 GEMM: 256x256 tile, BK=64, 8 waves, mfma_i32_32x32x32_i8 -------
// C = Xq[M,K]*Wq8[N,K]^T (i32 acc); out = acc*ts[row]*(rs[col]/127)+bias.
// FRAGMENT-LINEAR LDS (R7-verified, 0 bank conflicts): each fragment 1KB
// contiguous, ds_read = base+lane*16. glds dest linear; global source is the
// per-lane fragment gather (lane map: row=l&31, kseg=(l>>5)*16).
// R8 change: FULL-BODY READ LOOKAHEAD. All 12 ds_reads for tile T+1 issue in
// body T (2 fragment reg sets X/Y); every lgkm wait targets reads issued a
// full body (~2000 cyc) earlier -> LDS drains entirely under MFMA.
// Body T: lgkm(6)->8 MFMA kh0(T); RD12(T+1)+stage(T+3); lgkm(12)->8 MFMA
// kh1(T); vmcnt(4) [confirms stage(T+2) for body T+1's reads]; barrier.
// Ring-4 races: reads of slot (T+1)&3 are covered by stage(T+1) confirmed at
// end of body T-1; WAR of stage(T+3) onto slot (T-1)&3 covered by body T-1's
// lgkm drains + its barrier.

#define BKB 64
#define NKT (K_IN / BKB)   // 64
#define SLOT 32768
#define NSLOT 4

#define MFMA(a, b, c) c = __builtin_amdgcn_mfma_i32_32x32x32_i8(a, b, c, 0, 0, 0)

// 12 reads: kh0 frags first (A0-3,B0-1), then kh1 (A4-7,B2-3).
// A frag (mb,kh) at (mb*2+kh)*1024; B frag (nb,kh) at (nb*2+kh)*1024.
#define RD12(P, aB, bB)                        \
    P##_A0 = dsri<0>(aB);                      \
    P##_A1 = dsri<2048>(aB);                   \
    P##_A2 = dsri<4096>(aB);                   \
    P##_A3 = dsri<6144>(aB);                   \
    P##_B0 = dsri<0>(bB);                      \
    P##_B1 = dsri<2048>(bB);                   \
    P##_A4 = dsri<1024>(aB);                   \
    P##_A5 = dsri<3072>(aB);                   \
    P##_A6 = dsri<5120>(aB);                   \
    P##_A7 = dsri<7168>(aB);                   \
    P##_B2 = dsri<1024>(bB);                   \
    P##_B3 = dsri<3072>(bB);

#define CL8_0(P)                                              \
    MFMA(P##_A0, P##_B0, acc00); MFMA(P##_A0, P##_B1, acc01); \
    MFMA(P##_A1, P##_B0, acc10); MFMA(P##_A1, P##_B1, acc11); \
    MFMA(P##_A2, P##_B0, acc20); MFMA(P##_A2, P##_B1, acc21); \
    MFMA(P##_A3, P##_B0, acc30); MFMA(P##_A3, P##_B1, acc31);

#define CL8_1(P)                                              \
    MFMA(P##_A4, P##_B2, acc00); MFMA(P##_A4, P##_B3, acc01); \
    MFMA(P##_A5, P##_B2, acc10); MFMA(P##_A5, P##_B3, acc11); \
    MFMA(P##_A6, P##_B2, acc20); MFMA(P##_A6, P##_B3, acc21); \
    MFMA(P##_A7, P##_B2, acc30); MFMA(P##_A7, P##_B3, acc31);

#define GBODY(T, C, N, DO_STAGE)                                          \
    {                                                                     \
        asm volatile("s_waitcnt lgkmcnt(6)" ::: "memory");                \
        __builtin_amdgcn_sched_barrier(0);                                \
        __builtin_amdgcn_s_setprio(1);                                    \
        CL8_0(C)                                                          \
        __builtin_amdgcn_s_setprio(0);                                    \
        __builtin_amdgcn_sched_barrier(0);                                \
        const unsigned aN_ = aBase + (unsigned)((((T) + 1) & 3) * SLOT);  \
        const unsigned bN_ = bBase + (unsigned)((((T) + 1) & 3) * SLOT);  \
        RD12(N, aN_, bN_)                                                 \
        if (DO_STAGE) stageAB((T) + 3);                                   \
        asm volatile("s_waitcnt lgkmcnt(12)" ::: "memory");               \
        __builtin_amdgcn_sched_barrier(0);                                \
        __builtin_amdgcn_s_setprio(1);                                    \
        CL8_1(C)                                                          \
        __builtin_amdgcn_s_setprio(0);                                    \
        __builtin_amdgcn_sched_barrier(0);                                \
        if (DO_STAGE) { asm volatile("s_waitcnt vmcnt(4)" ::: "memory"); }\
        else          { asm volatile("s_waitcnt vmcnt(0)" ::: "memory"); }\
        __builtin_amdgcn_sched_barrier(0);                                \
        __builtin_amdgcn_s_barrier();                                     \
        __builtin_amdgcn_sched_barrier(0);                                \
    }

#define GFINAL(C)                                                         \
    {                                                                     \
        asm volatile("s_waitcnt lgkmcnt(6)" ::: "memory");                \
        __builtin_amdgcn_sched_barrier(0);                                \
        __builtin_amdgcn_s_setprio(1);                                    \
        CL8_0(C)                                                          \
        __builtin_amdgcn_s_setprio(0);                                    \
        asm volatile("s_waitcnt lgkmcnt(0)" ::: "memory");                \
        __builtin_amdgcn_sched_barrier(0);                                \
        __builtin_amdgcn_s_setprio(1);                                    \
        CL8_1(C)                                                          \
        __builtin_amdgcn_s_setprio(0);                                    \
        __builtin_amdgcn_sched_barrier(0);                                \
    }

__global__ __launch_bounds__(512, 2) void qgemm_i8p_kernel(
    const signed char* __restrict__ xq,
    const signed char* __restrict__ wq8,
    const float* __restrict__ tok_scale,
    const float* __restrict__ row_scales,
    const float* __restrict__ bias,
    float* __restrict__ out)
{
    __shared__ __align__(16) char smem[NSLOT * SLOT + 1024];  // 129 KiB

    const int tid = threadIdx.x;
    const int l = tid & 63;
    const int w = tid >> 6;      // 0..7
    const int wr = w >> 2;       // 0..1
    const int wc = w & 3;        // 0..3

    // XCD-aware bijective swizzle (nwg = 512, 512 % 8 == 0)
    const int bid = blockIdx.x;
    const int swz = (bid & 7) * 64 + (bid >> 3);
    const int bm = swz >> 4;     // 0..31
    const int bn = swz & 15;     // 0..15

    // ---- staging: wave w owns A frags {2w,2w+1} and B frags {2w,2w+1} ----
    const signed char* aS = xq  + (size_t)(bm * 256 + w * 32 + (l & 31)) * K_IN + (l >> 5) * 16;
    const signed char* bS = wq8 + (size_t)(bn * 256 + w * 32 + (l & 31)) * K_IN + (l >> 5) * 16;
    char* aDst = smem + w * 2048;              // A region [0,16K) of slot
    char* bDst = smem + 16384 + w * 2048;      // B region [16K,32K) of slot

    auto stageAB = [&](int tt) {
        const int sb = (tt & 3) * SLOT;
        const signed char* a0 = aS + tt * BKB;
        const signed char* b0 = bS + tt * BKB;
        __builtin_amdgcn_global_load_lds((const AS1 void*)a0,        (AS3 void*)(aDst + sb),        16, 0, 0);
        __builtin_amdgcn_global_load_lds((const AS1 void*)(a0 + 32), (AS3 void*)(aDst + sb + 1024), 16, 0, 0);
        __builtin_amdgcn_global_load_lds((const AS1 void*)b0,        (AS3 void*)(bDst + sb),        16, 0, 0);
        __builtin_amdgcn_global_load_lds((const AS1 void*)(b0 + 32), (AS3 void*)(bDst + sb + 1024), 16, 0, 0);
    };

    // ---- fragment-linear ds_read bases ----
    const unsigned sbase = (unsigned)(uintptr_t)(AS3 char*)smem;
    const unsigned aBase = sbase + (unsigned)(wr * 8192 + l * 16);           // + slot + (mb*2+kh)*1024
    const unsigned bBase = sbase + 16384u + (unsigned)(wc * 4096 + l * 16);  // + slot + (nb*2+kh)*1024

    i32x16 acc00 = {0}, acc01 = {0}, acc10 = {0}, acc11 = {0};
    i32x16 acc20 = {0}, acc21 = {0}, acc30 = {0}, acc31 = {0};

    i32x4 X_A0, X_A1, X_A2, X_A3, X_A4, X_A5, X_A6, X_A7, X_B0, X_B1, X_B2, X_B3;
    i32x4 Y_A0, Y_A1, Y_A2, Y_A3, Y_A4, Y_A5, Y_A6, Y_A7, Y_B0, Y_B1, Y_B2, Y_B3;

    // ---- prologue: stage tiles 0,1,2; confirm 0,1; read ALL of tile 0 ----
    stageAB(0); stageAB(1); stageAB(2);
    asm volatile("s_waitcnt vmcnt(4)" ::: "memory");
    __builtin_amdgcn_sched_barrier(0);
    __builtin_amdgcn_s_barrier();
    __builtin_amdgcn_sched_barrier(0);
    RD12(X, aBase, bBase)

    // ---- main loop: bodies 0..62 (X/Y alternate), body 63 = final ----
    for (int t = 0; t < 62; t += 2) {
        GBODY(t,     X, Y, (t + 3 < NKT));
        GBODY(t + 1, Y, X, (t + 4 < NKT));
    }
    GBODY(62, X, Y, false);
    GFINAL(Y)

    // ---- epilogue: tok scales via LDS, dequant, store ----
    float* ts = (float*)(smem + NSLOT * SLOT);
    if (tid < 256) ts[tid] = tok_scale[bm * 256 + tid];
    __syncthreads();

    const int cl = l & 31;
    const int rg4 = (l >> 5) * 4;
    const int gcol0 = bn * 256 + wc * 64;
    float cs[2], bb[2];
#pragma unroll
    for (int nb = 0; nb < 2; ++nb) {
        const int col = gcol0 + nb * 32 + cl;
        cs[nb] = row_scales[col] * (1.0f / 127.0f);
        bb[nb] = bias[col];
    }
    const i32x16* accs[4][2] = {{&acc00, &acc01}, {&acc10, &acc11},
                                {&acc20, &acc21}, {&acc30, &acc31}};
#pragma unroll
    for (int mb = 0; mb < 4; ++mb) {
#pragma unroll
        for (int reg = 0; reg < 16; ++reg) {
            const int rloc = wr * 128 + mb * 32 + (reg & 3) + 8 * (reg >> 2) + rg4;
            const float tsv = ts[rloc];
            float* orow = out + (size_t)(bm * 256 + rloc) * N_OUT + gcol0 + cl;
#pragma unroll
            for (int nb = 0; nb < 2; ++nb) {
                const int a = (*accs[mb][nb])[reg];
                orow[nb * 32] = (float)a * tsv * cs[nb] + bb[nb];
            }
        }
    }
}

// ---------------- launch ----------------

extern "C" void kernel_launch(void* const* d_in, const int* in_sizes, int n_in,
                              void* d_out, int out_size, void* d_ws, size_t ws_size,
                              hipStream_t stream) {
    const float* x = (const float*)d_in[0];
    const int* wq = (const int*)d_in[1];
    const float* row_scales = (const float*)d_in[2];
    const float* bias = (const float*)d_in[3];
    float* out = (float*)d_out;

    signed char* xq8 = (signed char*)d_ws;                       // 32 MiB
    signed char* wq8 = xq8 + (size_t)M_TOK * K_IN;               // 16 MiB
    float* tok_scale = (float*)(wq8 + (size_t)N_OUT * K_IN);     // 32 KiB
    (void)ws_size;

    quant_x_kernel<<<M_TOK, 256, 0, stream>>>(x, xq8, tok_scale);
    pack_w_kernel<<<2048, 256, 0, stream>>>(wq, wq8);

    const int nblocks = (M_TOK / 256) * (N_OUT / 256);  // 512
    qgemm_i8p_kernel<<<nblocks, 512, 0, stream>>>(
        xq8, wq8, tok_scale, row_scales, bias, out);
}